// Round 12
// baseline (405.718 us; speedup 1.0000x reference)
//
#include <hip/hip_runtime.h>
#include <hip/hip_bf16.h>

// Problem constants
#define BDIM 4
#define CDIM 2048
#define DDIM 512
#define HH   8
#define DKH  64
#define NROW (BDIM * CDIM)   // 8192

typedef unsigned short u16;
typedef unsigned int   u32;
typedef u16   u16x4  __attribute__((ext_vector_type(4)));
typedef u16   u16x8  __attribute__((ext_vector_type(8)));
typedef u32   u32x4  __attribute__((ext_vector_type(4)));
typedef __bf16 bf16x8 __attribute__((ext_vector_type(8)));
typedef __bf16 bf16x2 __attribute__((ext_vector_type(2)));
typedef float f32x4  __attribute__((ext_vector_type(4)));
typedef float f32x16 __attribute__((ext_vector_type(16)));

#define LOG2E 1.4426950408889634f

__device__ __forceinline__ u16 f2bf(float f) {
  union { float f; unsigned u; } x; x.f = f;
  unsigned u = x.u;
  u += 0x7fffu + ((u >> 16) & 1u);   // RNE
  return (u16)(u >> 16);
}
__device__ __forceinline__ float bf2f(u16 u) {
  return __builtin_bit_cast(float, (u32)u << 16);
}
__device__ __forceinline__ u32 pk2(float a, float b) {
  bf16x2 t; t[0] = (__bf16)a; t[1] = (__bf16)b;
  return __builtin_bit_cast(u32, t);
}
__device__ __forceinline__ float fexp2(float x) {
  float r;
  asm("v_exp_f32 %0, %1" : "=v"(r) : "v"(x));  // inputs bounded; no libm fixup
  return r;
}

__device__ __forceinline__ void gload_lds16(const u16* gp, u16* lp) {
  // async global->LDS, 16B per lane; LDS dest is wave-uniform base + lane*16
  __builtin_amdgcn_global_load_lds((__attribute__((address_space(1))) const void*)gp,
                                   (__attribute__((address_space(3))) void*)lp, 16, 0, 0);
}

// ---------------- LayerNorm body: one wave per row of 512 ------------------
__device__ __forceinline__ void ln_body(int bx, int tid,
                                        const float* __restrict__ x,
                                        const float* __restrict__ gamma,
                                        const float* __restrict__ beta,
                                        u16* __restrict__ y) {
  int gw = (bx * 256 + tid) >> 6;
  int l  = tid & 63;
  const float* xr = x + (size_t)gw * DDIM;
  float4 a = *(const float4*)(xr + l * 8);
  float4 b = *(const float4*)(xr + l * 8 + 4);
  float s = a.x + a.y + a.z + a.w + b.x + b.y + b.z + b.w;
  float q = a.x*a.x + a.y*a.y + a.z*a.z + a.w*a.w + b.x*b.x + b.y*b.y + b.z*b.z + b.w*b.w;
#pragma unroll
  for (int m = 1; m < 64; m <<= 1) { s += __shfl_xor(s, m); q += __shfl_xor(q, m); }
  float mu  = s * (1.0f / DDIM);
  float var = q * (1.0f / DDIM) - mu * mu;
  float rs  = rsqrtf(var + 1e-5f);
  float4 g0 = *(const float4*)(gamma + l * 8);
  float4 g1 = *(const float4*)(gamma + l * 8 + 4);
  float4 b0 = *(const float4*)(beta + l * 8);
  float4 b1 = *(const float4*)(beta + l * 8 + 4);
  u16x8 o;
  o[0] = f2bf((a.x - mu) * rs * g0.x + b0.x);
  o[1] = f2bf((a.y - mu) * rs * g0.y + b0.y);
  o[2] = f2bf((a.z - mu) * rs * g0.z + b0.z);
  o[3] = f2bf((a.w - mu) * rs * g0.w + b0.w);
  o[4] = f2bf((b.x - mu) * rs * g1.x + b1.x);
  o[5] = f2bf((b.y - mu) * rs * g1.y + b1.y);
  o[6] = f2bf((b.z - mu) * rs * g1.z + b1.z);
  o[7] = f2bf((b.w - mu) * rs * g1.w + b1.w);
  *(u16x8*)(y + (size_t)gw * DDIM + l * 8) = o;
}

__global__ __launch_bounds__(256) void ln_kernel(const float* __restrict__ x,
                                                 const float* __restrict__ gamma,
                                                 const float* __restrict__ beta,
                                                 u16* __restrict__ y) {
  ln_body(blockIdx.x, threadIdx.x, x, gamma, beta, y);
}

// ---- fused setup: ln1 (blocks 0-2047) + adj_transform (2048-3071) + weight
// transpose (3072-4095). All independent streaming work, one dispatch.
__global__ __launch_bounds__(256) void setup_kernel(const float* __restrict__ h,
                                                    const float* __restrict__ ln1g,
                                                    const float* __restrict__ ln1b,
                                                    u16* __restrict__ hn,
                                                    const float* __restrict__ adj,
                                                    u16* __restrict__ adjC,
                                                    const float* __restrict__ wqkv,
                                                    const float* __restrict__ wout,
                                                    const float* __restrict__ w1,
                                                    const float* __restrict__ w2,
                                                    u16* __restrict__ o_qkv,
                                                    u16* __restrict__ o_out,
                                                    u16* __restrict__ o_w1,
                                                    u16* __restrict__ o_w2) {
  const int bx = blockIdx.x;
  const int t = threadIdx.x;
  if (bx < 2048) {
    ln_body(bx, t, h, ln1g, ln1b, hn);
  } else if (bx < 3072) {
    // adjC[b][kt][q][hi][32]: value v=m*16+a*4+c from adj[b][q][kt*64+m*32+a*8+hi*4+c]
    const int f = bx - 2048;
    const int b = f >> 8, kt = (f >> 3) & 31;
    const int q0 = (f & 7) * 256;
    const int ch = t & 7, c16 = ch & 3, hi2 = ch >> 2, m = c16 >> 1;
    const int K0 = m * 32 + ((c16 * 2) & 3) * 8 + hi2 * 4;
#pragma unroll
    for (int itq = 0; itq < 8; ++itq) {
      int q = q0 + itq * 32 + (t >> 3);
      const float* src = adj + ((size_t)b * CDIM + q) * CDIM + kt * 64;
      f32x4 v0 = *(const f32x4*)(src + K0);
      f32x4 v1 = *(const f32x4*)(src + K0 + 8);
      u16x8 o;
      o[0] = f2bf(v0[0] * LOG2E); o[1] = f2bf(v0[1] * LOG2E);
      o[2] = f2bf(v0[2] * LOG2E); o[3] = f2bf(v0[3] * LOG2E);
      o[4] = f2bf(v1[0] * LOG2E); o[5] = f2bf(v1[1] * LOG2E);
      o[6] = f2bf(v1[2] * LOG2E); o[7] = f2bf(v1[3] * LOG2E);
      *(u16x8*)(adjC + ((size_t)(b * 32 + kt) * 2048 + q) * 64 + ch * 8) = o;
    }
  } else {
    int idx = (bx - 3072) * 256 + t;
    const float* w; u16* wt; int K, N;
    if (idx < 98304)       { w = wqkv; wt = o_qkv; K = 512;  N = 1536; }
    else if (idx < 131072) { idx -= 98304;  w = wout; wt = o_out; K = 512;  N = 512; }
    else if (idx < 196608) { idx -= 131072; w = w1;   wt = o_w1;  K = 512;  N = 1024; }
    else                   { idx -= 196608; w = w2;   wt = o_w2;  K = 1024; N = 512; }
    int kb = K >> 3;
    int n = idx / kb, k0 = (idx - n * kb) * 8;
    u16x8 o;
#pragma unroll
    for (int j = 0; j < 8; ++j) o[j] = f2bf(w[(size_t)(k0 + j) * N + n]);
    *(u16x8*)(wt + (size_t)n * K + k0) = o;
  }
}

// ------------- shared epilogue for both GEMM tiles --------------------------
template <int EPI>
__device__ __forceinline__ void gemm_epi(int row, int col, float val, int N,
                                         const float* __restrict__ res,
                                         float* __restrict__ outf,
                                         u16* __restrict__ outb,
                                         u16* __restrict__ outq,
                                         u16* __restrict__ outk,
                                         u16* __restrict__ outv) {
  if constexpr (EPI == 0) {
    int t = col >> 9, hh = (col >> 6) & 7, dk = col & 63;
    int bb = row >> 11, cc = row & 2047;
    if (t == 0) {
      val *= 0.125f * LOG2E;  // fold DK^-0.5 and log2(e) into q
      outq[(((size_t)bb * HH + hh) * CDIM + cc) * DKH + dk] = f2bf(val);
    } else if (t == 1) {
      outk[(((size_t)bb * HH + hh) * CDIM + cc) * DKH + dk] = f2bf(val);
    } else {  // V stored transposed: [bh][dk][C]
      outv[(((size_t)bb * HH + hh) * DKH + dk) * CDIM + cc] = f2bf(val);
    }
  } else if constexpr (EPI == 1) {
    size_t idx = (size_t)row * N + col;
    outf[idx] = val + res[idx];
  } else {
    float g = 0.5f * val * (1.0f + erff(val * 0.70710678118f));
    outb[(size_t)row * N + col] = f2bf(g);
  }
}

// XCD-bijective block remap: each XCD gets a contiguous bm-chunk so tile
// refetch is served by its LOCAL 4MB L2 (T1). Requires nwg % 8 == 0.
__device__ __forceinline__ void xcd_remap(int& bn, int& bm) {
  int nbn = gridDim.x;
  int nwg = nbn * gridDim.y;
  int flat = blockIdx.x + nbn * blockIdx.y;
  int virt = (flat & 7) * (nwg >> 3) + (flat >> 3);
  bn = virt % nbn;
  bm = virt / nbn;
}

// ---------------- GEMM 128x128, BK=64, 4 waves (2x2 of 64x64) ---------------
template <int EPI>
__global__ __launch_bounds__(256) void gemm128(const u16* __restrict__ A,
                                               const u16* __restrict__ Bt,
                                               const float* __restrict__ bias,
                                               const float* __restrict__ res,
                                               float* __restrict__ outf,
                                               u16* __restrict__ outb,
                                               u16* __restrict__ outq,
                                               u16* __restrict__ outk,
                                               u16* __restrict__ outv,
                                               int M, int N, int K) {
  __shared__ u16 As[2][128 * 64];
  __shared__ u16 Bs[2][128 * 64];
  const int tid = threadIdx.x;
  const int w = tid >> 6, l = tid & 63;
  const int l15 = l & 15, l4 = l >> 4, l7 = l15 & 7;
  int bn, bm;
  xcd_remap(bn, bm);
  const int wr = w >> 1, wc = w & 1;

  f32x4 acc[4][4] = {};

  const int sg = (l & 7) ^ (l >> 3);   // pre-swizzled source granule
  const u16* Ag = A  + (size_t)(bm * 128 + w * 32 + (l >> 3)) * K + sg * 8;
  const u16* Bg = Bt + (size_t)(bn * 128 + w * 32 + (l >> 3)) * K + sg * 8;

  auto stage = [&](int buf, int k0) {
#pragma unroll
    for (int i = 0; i < 4; ++i) {
      gload_lds16(Ag + (size_t)(8 * i) * K + k0, &As[buf][(w * 32 + 8 * i) * 64]);
      gload_lds16(Bg + (size_t)(8 * i) * K + k0, &Bs[buf][(w * 32 + 8 * i) * 64]);
    }
  };

  stage(0, 0);
  __syncthreads();
  int cur = 0;
  for (int k0 = 0; k0 < K; k0 += 64) {
    if (k0 + 64 < K) stage(cur ^ 1, k0 + 64);
#pragma unroll
    for (int s = 0; s < 2; ++s) {
      bf16x8 af[4], bf[4];
#pragma unroll
      for (int m = 0; m < 4; ++m)
        af[m] = *(const bf16x8*)(&As[cur][(wr * 64 + m * 16 + l15) * 64 + (((s * 4 + l4) ^ l7) * 8)]);
#pragma unroll
      for (int n = 0; n < 4; ++n)
        bf[n] = *(const bf16x8*)(&Bs[cur][(wc * 64 + n * 16 + l15) * 64 + (((s * 4 + l4) ^ l7) * 8)]);
#pragma unroll
      for (int m = 0; m < 4; ++m)
#pragma unroll
        for (int n = 0; n < 4; ++n)
          acc[m][n] = __builtin_amdgcn_mfma_f32_16x16x32_bf16(af[m], bf[n], acc[m][n], 0, 0, 0);
    }
    __syncthreads();
    cur ^= 1;
  }

#pragma unroll
  for (int m = 0; m < 4; ++m) {
    const int row0 = bm * 128 + wr * 64 + m * 16 + l4 * 4;
#pragma unroll
    for (int n = 0; n < 4; ++n) {
      const int col = bn * 128 + wc * 64 + n * 16 + l15;
      const float bv = bias[col];
#pragma unroll
      for (int r = 0; r < 4; ++r)
        gemm_epi<EPI>(row0 + r, col, acc[m][n][r] + bv, N, res, outf, outb, outq, outk, outv);
    }
  }
}

// ---------------- GEMM 64x128, BK=64, 4 waves -------------------------------
template <int EPI>
__global__ __launch_bounds__(256) void gemm64(const u16* __restrict__ A,
                                              const u16* __restrict__ Bt,
                                              const float* __restrict__ bias,
                                              const float* __restrict__ res,
                                              float* __restrict__ outf,
                                              u16* __restrict__ outb,
                                              u16* __restrict__ outq,
                                              u16* __restrict__ outk,
                                              u16* __restrict__ outv,
                                              int M, int N, int K) {
  __shared__ u16 As[2][64 * 64];
  __shared__ u16 Bs[2][128 * 64];
  const int tid = threadIdx.x;
  const int w = tid >> 6, l = tid & 63;
  const int l15 = l & 15, l4 = l >> 4, l7 = l15 & 7;
  int bn, bm;
  xcd_remap(bn, bm);

  f32x4 acc[4][2] = {};

  const int sg = (l & 7) ^ (l >> 3);   // pre-swizzled source granule
  const u16* Ag = A  + (size_t)(bm * 64  + w * 16 + (l >> 3)) * K + sg * 8;
  const u16* Bg = Bt + (size_t)(bn * 128 + w * 32 + (l >> 3)) * K + sg * 8;

  auto stage = [&](int buf, int k0) {
    gload_lds16(Ag + k0,                  &As[buf][(w * 16 + 0) * 64]);
    gload_lds16(Ag + (size_t)8 * K + k0,  &As[buf][(w * 16 + 8) * 64]);
    gload_lds16(Bg + k0,                  &Bs[buf][(w * 32 + 0) * 64]);
    gload_lds16(Bg + (size_t)8 * K + k0,  &Bs[buf][(w * 32 + 8) * 64]);
    gload_lds16(Bg + (size_t)16 * K + k0, &Bs[buf][(w * 32 + 16) * 64]);
    gload_lds16(Bg + (size_t)24 * K + k0, &Bs[buf][(w * 32 + 24) * 64]);
  };

  stage(0, 0);
  __syncthreads();
  int cur = 0;
  for (int k0 = 0; k0 < K; k0 += 64) {
    if (k0 + 64 < K) stage(cur ^ 1, k0 + 64);
#pragma unroll
    for (int s = 0; s < 2; ++s) {
      bf16x8 af[4], bf[2];
#pragma unroll
      for (int m = 0; m < 4; ++m)
        af[m] = *(const bf16x8*)(&As[cur][(m * 16 + l15) * 64 + (((s * 4 + l4) ^ l7) * 8)]);
#pragma unroll
      for (int n = 0; n < 2; ++n)
        bf[n] = *(const bf16x8*)(&Bs[cur][(w * 32 + n * 16 + l15) * 64 + (((s * 4 + l4) ^ l7) * 8)]);
#pragma unroll
      for (int m = 0; m < 4; ++m)
#pragma unroll
        for (int n = 0; n < 2; ++n)
          acc[m][n] = __builtin_amdgcn_mfma_f32_16x16x32_bf16(af[m], bf[n], acc[m][n], 0, 0, 0);
    }
    __syncthreads();
    cur ^= 1;
  }

#pragma unroll
  for (int m = 0; m < 4; ++m) {
    const int row0 = bm * 64 + m * 16 + l4 * 4;
#pragma unroll
    for (int n = 0; n < 2; ++n) {
      const int col = bn * 128 + w * 32 + n * 16 + l15;
      const float bv = bias[col];
#pragma unroll
      for (int r = 0; r < 4; ++r)
        gemm_epi<EPI>(row0 + r, col, acc[m][n][r] + bv, N, res, outf, outb, outq, outk, outv);
    }
  }
}

// ---------------- flash attention: 4-warp, full kt-range, 32x32 swapped -----
// 256 threads = 4 q-subtiles x 32 q-rows; all warps share one K/V double
// buffer (32KB LDS exactly -> 5 blocks/CU). (256,5) -> 102 VGPR cap,
// 20 waves/CU. No kh-combine: each warp owns the full k-range of its rows;
// row-sum redistribution via __shfl (no LDS).
__global__ __launch_bounds__(256, 5) void flash_attn(const u16* __restrict__ Q,
                                                     const u16* __restrict__ Kg,
                                                     const u16* __restrict__ Vt,
                                                     const u16* __restrict__ adjC,
                                                     u16* __restrict__ O) {
  __shared__ u16 Ks[2][64 * 64];
  __shared__ u16 Vs[2][64 * 64];
  const int flat = blockIdx.x + 16 * blockIdx.y;       // 512 blocks
  const int virt = (flat & 7) * 64 + (flat >> 3);      // XCD-contiguous remap
  const int qt = virt & 15;
  const int bh = virt >> 4;
  const int b = bh >> 3, hh = bh & 7;
  const int tid = threadIdx.x;
  const int w = tid >> 6, l = tid & 63;
  const int qg = w;
  const int q32 = l & 31, hi = l >> 5;
  const int qglob = qt * 128 + qg * 32 + q32;

  const u16* Qb = Q  + (size_t)bh * CDIM * DKH;
  const u16* Kb = Kg + (size_t)bh * CDIM * DKH;
  const u16* Vb = Vt + (size_t)bh * DKH * CDIM;  // [dk][C]

  // staging: warp qg stages rows [qg*16, qg*16+16) of the shared 64-row tile
  const int srow = qg * 16 + (l >> 3);
  const int sg   = (l & 7) ^ (l >> 3);  // pre-swizzled source granule
  const u16* Kg0 = Kb + (size_t)(srow + 0) * DKH + sg * 8;
  const u16* Kg1 = Kb + (size_t)(srow + 8) * DKH + sg * 8;
  const u16* Vg0 = Vb + (size_t)(srow + 0) * CDIM + sg * 8;
  const u16* Vg1 = Vb + (size_t)(srow + 8) * CDIM + sg * 8;

  bf16x8 qf[4];
#pragma unroll
  for (int s = 0; s < 4; ++s)
    qf[s] = *(const bf16x8*)(Qb + (size_t)qglob * DKH + s * 16 + hi * 8);

  const u16* adjQ = adjC + ((size_t)(b * 32) * 2048 + qglob) * 64 + hi * 32;

  f32x16 oa[2] = {};
  float lsum = 0.f;

  auto stage = [&](int buf, int kt) {
    gload_lds16(Kg0 + (size_t)kt * 4096, &Ks[buf][(qg * 16 + 0) * 64]);
    gload_lds16(Kg1 + (size_t)kt * 4096, &Ks[buf][(qg * 16 + 8) * 64]);
    gload_lds16(Vg0 + kt * 64, &Vs[buf][(qg * 16 + 0) * 64]);
    gload_lds16(Vg1 + kt * 64, &Vs[buf][(qg * 16 + 8) * 64]);
  };
  auto ajload = [&](u16x8* dst, int kt) {
    const u16* p = adjQ + (size_t)kt * 131072;  // 2048*64 u16 per kt
#pragma unroll
    for (int i = 0; i < 4; ++i) dst[i] = *(const u16x8*)(p + i * 8);
  };
  auto computeQK = [&](const u16* KsB, const u16x8* av, f32x16* sa) {
#pragma unroll
    for (int m = 0; m < 2; ++m)
#pragma unroll
      for (int r = 0; r < 16; ++r)
        sa[m][r] = bf2f(av[m * 2 + (r >> 3)][r & 7]);
    __builtin_amdgcn_s_setprio(1);
#pragma unroll
    for (int s = 0; s < 4; ++s)
#pragma unroll
      for (int m = 0; m < 2; ++m) {
        bf16x8 kf = *(const bf16x8*)(&KsB[(m * 32 + q32) * 64 + (((s * 2 + hi) ^ (q32 & 7)) * 8)]);
        sa[m] = __builtin_amdgcn_mfma_f32_32x32x16_bf16(kf, qf[s], sa[m], 0, 0, 0);
      }
    __builtin_amdgcn_s_setprio(0);
  };
  auto computePV = [&](const u16* VsB, f32x16* sa) {
#pragma unroll
    for (int m = 0; m < 2; ++m)
#pragma unroll
      for (int r = 0; r < 16; ++r) {
        float p = fexp2(sa[m][r]);
        sa[m][r] = p;
        lsum += p;
      }
    bf16x8 af[4];
#pragma unroll
    for (int m = 0; m < 2; ++m)
#pragma unroll
      for (int t2 = 0; t2 < 2; ++t2) {
        u32 w0 = pk2(sa[m][t2 * 8 + 0], sa[m][t2 * 8 + 1]);
        u32 w1 = pk2(sa[m][t2 * 8 + 2], sa[m][t2 * 8 + 3]);
        u32 w2 = pk2(sa[m][t2 * 8 + 4], sa[m][t2 * 8 + 5]);
        u32 w3 = pk2(sa[m][t2 * 8 + 6], sa[m][t2 * 8 + 7]);
        auto r02 = __builtin_amdgcn_permlane32_swap(w0, w2, false, false);
        auto r13 = __builtin_amdgcn_permlane32_swap(w1, w3, false, false);
        u32x4 aw;
        aw[0] = r02[0];
        aw[1] = r13[0];
        aw[2] = r02[1];
        aw[3] = r13[1];
        af[m * 2 + t2] = __builtin_bit_cast(bf16x8, aw);
      }
    __builtin_amdgcn_s_setprio(1);
#pragma unroll
    for (int s = 0; s < 4; ++s)
#pragma unroll
      for (int n = 0; n < 2; ++n) {
        bf16x8 vf = *(const bf16x8*)(&VsB[(n * 32 + q32) * 64 + (((s * 2 + hi) ^ (q32 & 7)) * 8)]);
        oa[n] = __builtin_amdgcn_mfma_f32_32x32x16_bf16(af[s], vf, oa[n], 0, 0, 0);
      }
    __builtin_amdgcn_s_setprio(0);
  };

  u16x8 avA[4], avB[4];
  f32x16 sa[2];
  stage(0, 0);
  ajload(avA, 0);
  __syncthreads();
#pragma unroll 1
  for (int it = 0; it < 16; ++it) {
    int kt = it * 2;
    stage(1, kt + 1);
    computeQK(&Ks[0][0], avA, sa);
    ajload(avB, kt + 1);           // prefetch next adj under PV
    computePV(&Vs[0][0], sa);
    __syncthreads();
    if (kt + 2 < 32) stage(0, kt + 2);
    computeQK(&Ks[1][0], avB, sa);
    if (kt + 2 < 32) ajload(avA, kt + 2);
    computePV(&Vs[1][0], sa);
    __syncthreads();
  }

  // full row sum: lane + partner(l^32) hold complementary k-halves
  lsum += __shfl_xor(lsum, 32);
  float inv = 1.0f / lsum;

  // write attn_out; per-row inv fetched by shuffle (row qloc lives at lane q32=qloc)
#pragma unroll
  for (int n = 0; n < 2; ++n)
#pragma unroll
    for (int r = 0; r < 16; ++r) {
      int qloc = (r & 3) + 8 * (r >> 2) + 4 * hi;
      float invr = __shfl(inv, (l & 32) | qloc);
      int row = qt * 128 + qg * 32 + qloc;
      O[((size_t)b * CDIM + row) * DDIM + hh * 64 + n * 32 + q32] = f2bf(oa[n][r] * invr);
    }
}

extern "C" void kernel_launch(void* const* d_in, const int* in_sizes, int n_in,
                              void* d_out, int out_size, void* d_ws, size_t ws_size,
                              hipStream_t stream) {
  const float* h      = (const float*)d_in[0];
  const float* adj    = (const float*)d_in[1];
  const float* w_qkv  = (const float*)d_in[2];
  const float* b_qkv  = (const float*)d_in[3];
  const float* w_out  = (const float*)d_in[4];
  const float* b_out  = (const float*)d_in[5];
  const float* ln1g   = (const float*)d_in[6];
  const float* ln1b   = (const float*)d_in[7];
  const float* ln2g   = (const float*)d_in[8];
  const float* ln2b   = (const float*)d_in[9];
  const float* w1     = (const float*)d_in[10];
  const float* b1     = (const float*)d_in[11];
  const float* w2     = (const float*)d_in[12];
  const float* b2     = (const float*)d_in[13];
  float* out = (float*)d_out;

  char* ws = (char*)d_ws;
  u16* adjC  = (u16*)(ws);                      // 32 MiB exactly, dead after flash
  u16* hn    = (u16*)(ws + 33554432);           // 8 MiB; reused as ff_in
  u16* qb    = (u16*)(ws + 41943040);           // q head-major; later ffmid spans qb+kb
  u16* kb    = (u16*)(ws + 50331648);
  u16* vt    = (u16*)(ws + 58720256);           // V transposed [bh][dk][C]
  u16* attn  = (u16*)(ws + 67108864);
  u16* wqkvt = (u16*)(ws + 75497472);           // 1536x512 bf16 = 1.5MiB
  u16* woutt = (u16*)(ws + 77070336);           // 512x512
  u16* w1t   = (u16*)(ws + 77594624);           // 1024x512
  u16* w2t   = (u16*)(ws + 78643200);           // 512x1024
  u16* ffin  = hn;
  u16* ffmid = qb;   // 16MiB spans qb+kb (both dead after flash_attn)

  setup_kernel<<<4096, 256, 0, stream>>>(h, ln1g, ln1b, hn, adj, adjC,
                                         w_qkv, w_out, w1, w2,
                                         wqkvt, woutt, w1t, w2t);

  gemm128<0><<<dim3(12, 64), 256, 0, stream>>>(hn, wqkvt, b_qkv, nullptr,
                                               nullptr, nullptr, qb, kb, vt,
                                               NROW, 3 * DDIM, DDIM);

  flash_attn<<<dim3(16, 32), 256, 0, stream>>>(qb, kb, vt, adjC, attn);

  gemm64<1><<<dim3(4, 128), 256, 0, stream>>>(attn, woutt, b_out, h,
                                              out, nullptr, nullptr, nullptr, nullptr,
                                              NROW, DDIM, DDIM);

  ln_kernel<<<2048, 256, 0, stream>>>(out, ln2g, ln2b, ffin);

  gemm128<2><<<dim3(8, 64), 256, 0, stream>>>(ffin, w1t, b1, nullptr,
                                              nullptr, ffmid, nullptr, nullptr, nullptr,
                                              NROW, 2 * DDIM, DDIM);

  gemm64<1><<<dim3(4, 128), 256, 0, stream>>>(ffmid, w2t, b2, out,
                                              out, nullptr, nullptr, nullptr, nullptr,
                                              NROW, DDIM, 2 * DDIM);
}

// Round 13
// 192.357 us; speedup vs baseline: 2.1092x; 2.1092x over previous
//
#include <hip/hip_runtime.h>
#include <hip/hip_bf16.h>

// Problem constants
#define BDIM 4
#define CDIM 2048
#define DDIM 512
#define HH   8
#define DKH  64
#define NROW (BDIM * CDIM)   // 8192

typedef unsigned short u16;
typedef unsigned int   u32;
typedef u16   u16x4  __attribute__((ext_vector_type(4)));
typedef u16   u16x8  __attribute__((ext_vector_type(8)));
typedef u32   u32x4  __attribute__((ext_vector_type(4)));
typedef __bf16 bf16x8 __attribute__((ext_vector_type(8)));
typedef __bf16 bf16x2 __attribute__((ext_vector_type(2)));
typedef float f32x4  __attribute__((ext_vector_type(4)));
typedef float f32x16 __attribute__((ext_vector_type(16)));

#define LOG2E 1.4426950408889634f

__device__ __forceinline__ u16 f2bf(float f) {
  union { float f; unsigned u; } x; x.f = f;
  unsigned u = x.u;
  u += 0x7fffu + ((u >> 16) & 1u);   // RNE
  return (u16)(u >> 16);
}
__device__ __forceinline__ float bf2f(u16 u) {
  return __builtin_bit_cast(float, (u32)u << 16);
}
__device__ __forceinline__ u32 pk2(float a, float b) {
  bf16x2 t; t[0] = (__bf16)a; t[1] = (__bf16)b;
  return __builtin_bit_cast(u32, t);
}
__device__ __forceinline__ float fexp2(float x) {
  float r;
  asm("v_exp_f32 %0, %1" : "=v"(r) : "v"(x));  // inputs bounded; no libm fixup
  return r;
}

__device__ __forceinline__ void gload_lds16(const u16* gp, u16* lp) {
  // async global->LDS, 16B per lane; LDS dest is wave-uniform base + lane*16
  __builtin_amdgcn_global_load_lds((__attribute__((address_space(1))) const void*)gp,
                                   (__attribute__((address_space(3))) void*)lp, 16, 0, 0);
}

// ---------------- LayerNorm body: one wave per row of 512 ------------------
__device__ __forceinline__ void ln_body(int bx, int tid,
                                        const float* __restrict__ x,
                                        const float* __restrict__ gamma,
                                        const float* __restrict__ beta,
                                        u16* __restrict__ y) {
  int gw = (bx * 256 + tid) >> 6;
  int l  = tid & 63;
  const float* xr = x + (size_t)gw * DDIM;
  float4 a = *(const float4*)(xr + l * 8);
  float4 b = *(const float4*)(xr + l * 8 + 4);
  float s = a.x + a.y + a.z + a.w + b.x + b.y + b.z + b.w;
  float q = a.x*a.x + a.y*a.y + a.z*a.z + a.w*a.w + b.x*b.x + b.y*b.y + b.z*b.z + b.w*b.w;
#pragma unroll
  for (int m = 1; m < 64; m <<= 1) { s += __shfl_xor(s, m); q += __shfl_xor(q, m); }
  float mu  = s * (1.0f / DDIM);
  float var = q * (1.0f / DDIM) - mu * mu;
  float rs  = rsqrtf(var + 1e-5f);
  float4 g0 = *(const float4*)(gamma + l * 8);
  float4 g1 = *(const float4*)(gamma + l * 8 + 4);
  float4 b0 = *(const float4*)(beta + l * 8);
  float4 b1 = *(const float4*)(beta + l * 8 + 4);
  u16x8 o;
  o[0] = f2bf((a.x - mu) * rs * g0.x + b0.x);
  o[1] = f2bf((a.y - mu) * rs * g0.y + b0.y);
  o[2] = f2bf((a.z - mu) * rs * g0.z + b0.z);
  o[3] = f2bf((a.w - mu) * rs * g0.w + b0.w);
  o[4] = f2bf((b.x - mu) * rs * g1.x + b1.x);
  o[5] = f2bf((b.y - mu) * rs * g1.y + b1.y);
  o[6] = f2bf((b.z - mu) * rs * g1.z + b1.z);
  o[7] = f2bf((b.w - mu) * rs * g1.w + b1.w);
  *(u16x8*)(y + (size_t)gw * DDIM + l * 8) = o;
}

__global__ __launch_bounds__(256) void ln_kernel(const float* __restrict__ x,
                                                 const float* __restrict__ gamma,
                                                 const float* __restrict__ beta,
                                                 u16* __restrict__ y) {
  ln_body(blockIdx.x, threadIdx.x, x, gamma, beta, y);
}

// ---- fused setup: ln1 (blocks 0-2047) + adj_transform (2048-3071) + weight
// transpose (3072-4095). All independent streaming work, one dispatch.
__global__ __launch_bounds__(256) void setup_kernel(const float* __restrict__ h,
                                                    const float* __restrict__ ln1g,
                                                    const float* __restrict__ ln1b,
                                                    u16* __restrict__ hn,
                                                    const float* __restrict__ adj,
                                                    u16* __restrict__ adjC,
                                                    const float* __restrict__ wqkv,
                                                    const float* __restrict__ wout,
                                                    const float* __restrict__ w1,
                                                    const float* __restrict__ w2,
                                                    u16* __restrict__ o_qkv,
                                                    u16* __restrict__ o_out,
                                                    u16* __restrict__ o_w1,
                                                    u16* __restrict__ o_w2) {
  const int bx = blockIdx.x;
  const int t = threadIdx.x;
  if (bx < 2048) {
    ln_body(bx, t, h, ln1g, ln1b, hn);
  } else if (bx < 3072) {
    // adjC[b][kt][q][hi][32]: value v=m*16+a*4+c from adj[b][q][kt*64+m*32+a*8+hi*4+c]
    const int f = bx - 2048;
    const int b = f >> 8, kt = (f >> 3) & 31;
    const int q0 = (f & 7) * 256;
    const int ch = t & 7, c16 = ch & 3, hi2 = ch >> 2, m = c16 >> 1;
    const int K0 = m * 32 + ((c16 * 2) & 3) * 8 + hi2 * 4;
#pragma unroll
    for (int itq = 0; itq < 8; ++itq) {
      int q = q0 + itq * 32 + (t >> 3);
      const float* src = adj + ((size_t)b * CDIM + q) * CDIM + kt * 64;
      f32x4 v0 = *(const f32x4*)(src + K0);
      f32x4 v1 = *(const f32x4*)(src + K0 + 8);
      u16x8 o;
      o[0] = f2bf(v0[0] * LOG2E); o[1] = f2bf(v0[1] * LOG2E);
      o[2] = f2bf(v0[2] * LOG2E); o[3] = f2bf(v0[3] * LOG2E);
      o[4] = f2bf(v1[0] * LOG2E); o[5] = f2bf(v1[1] * LOG2E);
      o[6] = f2bf(v1[2] * LOG2E); o[7] = f2bf(v1[3] * LOG2E);
      *(u16x8*)(adjC + ((size_t)(b * 32 + kt) * 2048 + q) * 64 + ch * 8) = o;
    }
  } else {
    int idx = (bx - 3072) * 256 + t;
    const float* w; u16* wt; int K, N;
    if (idx < 98304)       { w = wqkv; wt = o_qkv; K = 512;  N = 1536; }
    else if (idx < 131072) { idx -= 98304;  w = wout; wt = o_out; K = 512;  N = 512; }
    else if (idx < 196608) { idx -= 131072; w = w1;   wt = o_w1;  K = 512;  N = 1024; }
    else                   { idx -= 196608; w = w2;   wt = o_w2;  K = 1024; N = 512; }
    int kb = K >> 3;
    int n = idx / kb, k0 = (idx - n * kb) * 8;
    u16x8 o;
#pragma unroll
    for (int j = 0; j < 8; ++j) o[j] = f2bf(w[(size_t)(k0 + j) * N + n]);
    *(u16x8*)(wt + (size_t)n * K + k0) = o;
  }
}

// ------------- shared epilogue for both GEMM tiles --------------------------
template <int EPI>
__device__ __forceinline__ void gemm_epi(int row, int col, float val, int N,
                                         const float* __restrict__ res,
                                         float* __restrict__ outf,
                                         u16* __restrict__ outb,
                                         u16* __restrict__ outq,
                                         u16* __restrict__ outk,
                                         u16* __restrict__ outv) {
  if constexpr (EPI == 0) {
    int t = col >> 9, hh = (col >> 6) & 7, dk = col & 63;
    int bb = row >> 11, cc = row & 2047;
    if (t == 0) {
      val *= 0.125f * LOG2E;  // fold DK^-0.5 and log2(e) into q
      outq[(((size_t)bb * HH + hh) * CDIM + cc) * DKH + dk] = f2bf(val);
    } else if (t == 1) {
      outk[(((size_t)bb * HH + hh) * CDIM + cc) * DKH + dk] = f2bf(val);
    } else {  // V stored transposed: [bh][dk][C]
      outv[(((size_t)bb * HH + hh) * DKH + dk) * CDIM + cc] = f2bf(val);
    }
  } else if constexpr (EPI == 1) {
    size_t idx = (size_t)row * N + col;
    outf[idx] = val + res[idx];
  } else {
    float g = 0.5f * val * (1.0f + erff(val * 0.70710678118f));
    outb[(size_t)row * N + col] = f2bf(g);
  }
}

// XCD-bijective block remap: each XCD gets a contiguous bm-chunk so tile
// refetch is served by its LOCAL 4MB L2 (T1). Requires nwg % 8 == 0.
__device__ __forceinline__ void xcd_remap(int& bn, int& bm) {
  int nbn = gridDim.x;
  int nwg = nbn * gridDim.y;
  int flat = blockIdx.x + nbn * blockIdx.y;
  int virt = (flat & 7) * (nwg >> 3) + (flat >> 3);
  bn = virt % nbn;
  bm = virt / nbn;
}

// ---------------- GEMM 128x128, BK=64, 4 waves (2x2 of 64x64) ---------------
template <int EPI>
__global__ __launch_bounds__(256) void gemm128(const u16* __restrict__ A,
                                               const u16* __restrict__ Bt,
                                               const float* __restrict__ bias,
                                               const float* __restrict__ res,
                                               float* __restrict__ outf,
                                               u16* __restrict__ outb,
                                               u16* __restrict__ outq,
                                               u16* __restrict__ outk,
                                               u16* __restrict__ outv,
                                               int M, int N, int K) {
  __shared__ u16 As[2][128 * 64];
  __shared__ u16 Bs[2][128 * 64];
  const int tid = threadIdx.x;
  const int w = tid >> 6, l = tid & 63;
  const int l15 = l & 15, l4 = l >> 4, l7 = l15 & 7;
  int bn, bm;
  xcd_remap(bn, bm);
  const int wr = w >> 1, wc = w & 1;

  f32x4 acc[4][4] = {};

  const int sg = (l & 7) ^ (l >> 3);   // pre-swizzled source granule
  const u16* Ag = A  + (size_t)(bm * 128 + w * 32 + (l >> 3)) * K + sg * 8;
  const u16* Bg = Bt + (size_t)(bn * 128 + w * 32 + (l >> 3)) * K + sg * 8;

  auto stage = [&](int buf, int k0) {
#pragma unroll
    for (int i = 0; i < 4; ++i) {
      gload_lds16(Ag + (size_t)(8 * i) * K + k0, &As[buf][(w * 32 + 8 * i) * 64]);
      gload_lds16(Bg + (size_t)(8 * i) * K + k0, &Bs[buf][(w * 32 + 8 * i) * 64]);
    }
  };

  stage(0, 0);
  __syncthreads();
  int cur = 0;
  for (int k0 = 0; k0 < K; k0 += 64) {
    if (k0 + 64 < K) stage(cur ^ 1, k0 + 64);
#pragma unroll
    for (int s = 0; s < 2; ++s) {
      bf16x8 af[4], bf[4];
#pragma unroll
      for (int m = 0; m < 4; ++m)
        af[m] = *(const bf16x8*)(&As[cur][(wr * 64 + m * 16 + l15) * 64 + (((s * 4 + l4) ^ l7) * 8)]);
#pragma unroll
      for (int n = 0; n < 4; ++n)
        bf[n] = *(const bf16x8*)(&Bs[cur][(wc * 64 + n * 16 + l15) * 64 + (((s * 4 + l4) ^ l7) * 8)]);
#pragma unroll
      for (int m = 0; m < 4; ++m)
#pragma unroll
        for (int n = 0; n < 4; ++n)
          acc[m][n] = __builtin_amdgcn_mfma_f32_16x16x32_bf16(af[m], bf[n], acc[m][n], 0, 0, 0);
    }
    __syncthreads();
    cur ^= 1;
  }

#pragma unroll
  for (int m = 0; m < 4; ++m) {
    const int row0 = bm * 128 + wr * 64 + m * 16 + l4 * 4;
#pragma unroll
    for (int n = 0; n < 4; ++n) {
      const int col = bn * 128 + wc * 64 + n * 16 + l15;
      const float bv = bias[col];
#pragma unroll
      for (int r = 0; r < 4; ++r)
        gemm_epi<EPI>(row0 + r, col, acc[m][n][r] + bv, N, res, outf, outb, outq, outk, outv);
    }
  }
}

// ---------------- GEMM 64x128, BK=64, 4 waves -------------------------------
template <int EPI>
__global__ __launch_bounds__(256) void gemm64(const u16* __restrict__ A,
                                              const u16* __restrict__ Bt,
                                              const float* __restrict__ bias,
                                              const float* __restrict__ res,
                                              float* __restrict__ outf,
                                              u16* __restrict__ outb,
                                              u16* __restrict__ outq,
                                              u16* __restrict__ outk,
                                              u16* __restrict__ outv,
                                              int M, int N, int K) {
  __shared__ u16 As[2][64 * 64];
  __shared__ u16 Bs[2][128 * 64];
  const int tid = threadIdx.x;
  const int w = tid >> 6, l = tid & 63;
  const int l15 = l & 15, l4 = l >> 4, l7 = l15 & 7;
  int bn, bm;
  xcd_remap(bn, bm);

  f32x4 acc[4][2] = {};

  const int sg = (l & 7) ^ (l >> 3);   // pre-swizzled source granule
  const u16* Ag = A  + (size_t)(bm * 64  + w * 16 + (l >> 3)) * K + sg * 8;
  const u16* Bg = Bt + (size_t)(bn * 128 + w * 32 + (l >> 3)) * K + sg * 8;

  auto stage = [&](int buf, int k0) {
    gload_lds16(Ag + k0,                  &As[buf][(w * 16 + 0) * 64]);
    gload_lds16(Ag + (size_t)8 * K + k0,  &As[buf][(w * 16 + 8) * 64]);
    gload_lds16(Bg + k0,                  &Bs[buf][(w * 32 + 0) * 64]);
    gload_lds16(Bg + (size_t)8 * K + k0,  &Bs[buf][(w * 32 + 8) * 64]);
    gload_lds16(Bg + (size_t)16 * K + k0, &Bs[buf][(w * 32 + 16) * 64]);
    gload_lds16(Bg + (size_t)24 * K + k0, &Bs[buf][(w * 32 + 24) * 64]);
  };

  stage(0, 0);
  __syncthreads();
  int cur = 0;
  for (int k0 = 0; k0 < K; k0 += 64) {
    if (k0 + 64 < K) stage(cur ^ 1, k0 + 64);
#pragma unroll
    for (int s = 0; s < 2; ++s) {
      bf16x8 af[4], bf[2];
#pragma unroll
      for (int m = 0; m < 4; ++m)
        af[m] = *(const bf16x8*)(&As[cur][(m * 16 + l15) * 64 + (((s * 4 + l4) ^ l7) * 8)]);
#pragma unroll
      for (int n = 0; n < 2; ++n)
        bf[n] = *(const bf16x8*)(&Bs[cur][(w * 32 + n * 16 + l15) * 64 + (((s * 4 + l4) ^ l7) * 8)]);
#pragma unroll
      for (int m = 0; m < 4; ++m)
#pragma unroll
        for (int n = 0; n < 2; ++n)
          acc[m][n] = __builtin_amdgcn_mfma_f32_16x16x32_bf16(af[m], bf[n], acc[m][n], 0, 0, 0);
    }
    __syncthreads();
    cur ^= 1;
  }

#pragma unroll
  for (int m = 0; m < 4; ++m) {
    const int row0 = bm * 64 + m * 16 + l4 * 4;
#pragma unroll
    for (int n = 0; n < 2; ++n) {
      const int col = bn * 128 + w * 32 + n * 16 + l15;
      const float bv = bias[col];
#pragma unroll
      for (int r = 0; r < 4; ++r)
        gemm_epi<EPI>(row0 + r, col, acc[m][n][r] + bv, N, res, outf, outb, outq, outk, outv);
    }
  }
}

// ---------------- flash attention: 4-warp, full kt-range, 32x32 swapped -----
// 256 threads = 4 q-subtiles x 32 q-rows; all warps share one K/V double
// buffer (32KB LDS). NO second launch_bounds arg: the natural VGPR count
// (~96-110) gives 4-5 blocks/CU (16-20 waves) without forcing a spill.
// (R12's (256,5) forced a 48-VGPR budget -> 403MB scratch spill, 4.3x slower.)
__global__ __launch_bounds__(256) void flash_attn(const u16* __restrict__ Q,
                                                  const u16* __restrict__ Kg,
                                                  const u16* __restrict__ Vt,
                                                  const u16* __restrict__ adjC,
                                                  u16* __restrict__ O) {
  __shared__ u16 Ks[2][64 * 64];
  __shared__ u16 Vs[2][64 * 64];
  const int flat = blockIdx.x + 16 * blockIdx.y;       // 512 blocks
  const int virt = (flat & 7) * 64 + (flat >> 3);      // XCD-contiguous remap
  const int qt = virt & 15;
  const int bh = virt >> 4;
  const int b = bh >> 3, hh = bh & 7;
  const int tid = threadIdx.x;
  const int w = tid >> 6, l = tid & 63;
  const int qg = w;
  const int q32 = l & 31, hi = l >> 5;
  const int qglob = qt * 128 + qg * 32 + q32;

  const u16* Qb = Q  + (size_t)bh * CDIM * DKH;
  const u16* Kb = Kg + (size_t)bh * CDIM * DKH;
  const u16* Vb = Vt + (size_t)bh * DKH * CDIM;  // [dk][C]

  // staging: warp qg stages rows [qg*16, qg*16+16) of the shared 64-row tile
  const int srow = qg * 16 + (l >> 3);
  const int sg   = (l & 7) ^ (l >> 3);  // pre-swizzled source granule
  const u16* Kg0 = Kb + (size_t)(srow + 0) * DKH + sg * 8;
  const u16* Kg1 = Kb + (size_t)(srow + 8) * DKH + sg * 8;
  const u16* Vg0 = Vb + (size_t)(srow + 0) * CDIM + sg * 8;
  const u16* Vg1 = Vb + (size_t)(srow + 8) * CDIM + sg * 8;

  bf16x8 qf[4];
#pragma unroll
  for (int s = 0; s < 4; ++s)
    qf[s] = *(const bf16x8*)(Qb + (size_t)qglob * DKH + s * 16 + hi * 8);

  const u16* adjQ = adjC + ((size_t)(b * 32) * 2048 + qglob) * 64 + hi * 32;

  f32x16 oa[2] = {};
  float lsum = 0.f;

  auto stage = [&](int buf, int kt) {
    gload_lds16(Kg0 + (size_t)kt * 4096, &Ks[buf][(qg * 16 + 0) * 64]);
    gload_lds16(Kg1 + (size_t)kt * 4096, &Ks[buf][(qg * 16 + 8) * 64]);
    gload_lds16(Vg0 + kt * 64, &Vs[buf][(qg * 16 + 0) * 64]);
    gload_lds16(Vg1 + kt * 64, &Vs[buf][(qg * 16 + 8) * 64]);
  };
  auto ajload = [&](u16x8* dst, int kt) {
    const u16* p = adjQ + (size_t)kt * 131072;  // 2048*64 u16 per kt
#pragma unroll
    for (int i = 0; i < 4; ++i) dst[i] = *(const u16x8*)(p + i * 8);
  };
  auto computeQK = [&](const u16* KsB, const u16x8* av, f32x16* sa) {
#pragma unroll
    for (int m = 0; m < 2; ++m)
#pragma unroll
      for (int r = 0; r < 16; ++r)
        sa[m][r] = bf2f(av[m * 2 + (r >> 3)][r & 7]);
    __builtin_amdgcn_s_setprio(1);
#pragma unroll
    for (int s = 0; s < 4; ++s)
#pragma unroll
      for (int m = 0; m < 2; ++m) {
        bf16x8 kf = *(const bf16x8*)(&KsB[(m * 32 + q32) * 64 + (((s * 2 + hi) ^ (q32 & 7)) * 8)]);
        sa[m] = __builtin_amdgcn_mfma_f32_32x32x16_bf16(kf, qf[s], sa[m], 0, 0, 0);
      }
    __builtin_amdgcn_s_setprio(0);
  };
  auto computePV = [&](const u16* VsB, f32x16* sa) {
#pragma unroll
    for (int m = 0; m < 2; ++m)
#pragma unroll
      for (int r = 0; r < 16; ++r) {
        float p = fexp2(sa[m][r]);
        sa[m][r] = p;
        lsum += p;
      }
    bf16x8 af[4];
#pragma unroll
    for (int m = 0; m < 2; ++m)
#pragma unroll
      for (int t2 = 0; t2 < 2; ++t2) {
        u32 w0 = pk2(sa[m][t2 * 8 + 0], sa[m][t2 * 8 + 1]);
        u32 w1 = pk2(sa[m][t2 * 8 + 2], sa[m][t2 * 8 + 3]);
        u32 w2 = pk2(sa[m][t2 * 8 + 4], sa[m][t2 * 8 + 5]);
        u32 w3 = pk2(sa[m][t2 * 8 + 6], sa[m][t2 * 8 + 7]);
        auto r02 = __builtin_amdgcn_permlane32_swap(w0, w2, false, false);
        auto r13 = __builtin_amdgcn_permlane32_swap(w1, w3, false, false);
        u32x4 aw;
        aw[0] = r02[0];
        aw[1] = r13[0];
        aw[2] = r02[1];
        aw[3] = r13[1];
        af[m * 2 + t2] = __builtin_bit_cast(bf16x8, aw);
      }
    __builtin_amdgcn_s_setprio(1);
#pragma unroll
    for (int s = 0; s < 4; ++s)
#pragma unroll
      for (int n = 0; n < 2; ++n) {
        bf16x8 vf = *(const bf16x8*)(&VsB[(n * 32 + q32) * 64 + (((s * 2 + hi) ^ (q32 & 7)) * 8)]);
        oa[n] = __builtin_amdgcn_mfma_f32_32x32x16_bf16(af[s], vf, oa[n], 0, 0, 0);
      }
    __builtin_amdgcn_s_setprio(0);
  };

  u16x8 avA[4], avB[4];
  f32x16 sa[2];
  stage(0, 0);
  ajload(avA, 0);
  __syncthreads();
#pragma unroll 1
  for (int it = 0; it < 16; ++it) {
    int kt = it * 2;
    stage(1, kt + 1);
    computeQK(&Ks[0][0], avA, sa);
    ajload(avB, kt + 1);           // prefetch next adj under PV
    computePV(&Vs[0][0], sa);
    __syncthreads();
    if (kt + 2 < 32) stage(0, kt + 2);
    computeQK(&Ks[1][0], avB, sa);
    if (kt + 2 < 32) ajload(avA, kt + 2);
    computePV(&Vs[1][0], sa);
    __syncthreads();
  }

  // full row sum: lane + partner(l^32) hold complementary k-halves
  lsum += __shfl_xor(lsum, 32);
  float inv = 1.0f / lsum;

  // write attn_out; per-row inv fetched by shuffle (row qloc lives at lane q32=qloc)
#pragma unroll
  for (int n = 0; n < 2; ++n)
#pragma unroll
    for (int r = 0; r < 16; ++r) {
      int qloc = (r & 3) + 8 * (r >> 2) + 4 * hi;
      float invr = __shfl(inv, (l & 32) | qloc);
      int row = qt * 128 + qg * 32 + qloc;
      O[((size_t)b * CDIM + row) * DDIM + hh * 64 + n * 32 + q32] = f2bf(oa[n][r] * invr);
    }
}

extern "C" void kernel_launch(void* const* d_in, const int* in_sizes, int n_in,
                              void* d_out, int out_size, void* d_ws, size_t ws_size,
                              hipStream_t stream) {
  const float* h      = (const float*)d_in[0];
  const float* adj    = (const float*)d_in[1];
  const float* w_qkv  = (const float*)d_in[2];
  const float* b_qkv  = (const float*)d_in[3];
  const float* w_out  = (const float*)d_in[4];
  const float* b_out  = (const float*)d_in[5];
  const float* ln1g   = (const float*)d_in[6];
  const float* ln1b   = (const float*)d_in[7];
  const float* ln2g   = (const float*)d_in[8];
  const float* ln2b   = (const float*)d_in[9];
  const float* w1     = (const float*)d_in[10];
  const float* b1     = (const float*)d_in[11];
  const float* w2     = (const float*)d_in[12];
  const float* b2     = (const float*)d_in[13];
  float* out = (float*)d_out;

  char* ws = (char*)d_ws;
  u16* adjC  = (u16*)(ws);                      // 32 MiB exactly, dead after flash
  u16* hn    = (u16*)(ws + 33554432);           // 8 MiB; reused as ff_in
  u16* qb    = (u16*)(ws + 41943040);           // q head-major; later ffmid spans qb+kb
  u16* kb    = (u16*)(ws + 50331648);
  u16* vt    = (u16*)(ws + 58720256);           // V transposed [bh][dk][C]
  u16* attn  = (u16*)(ws + 67108864);
  u16* wqkvt = (u16*)(ws + 75497472);           // 1536x512 bf16 = 1.5MiB
  u16* woutt = (u16*)(ws + 77070336);           // 512x512
  u16* w1t   = (u16*)(ws + 77594624);           // 1024x512
  u16* w2t   = (u16*)(ws + 78643200);           // 512x1024
  u16* ffin  = hn;
  u16* ffmid = qb;   // 16MiB spans qb+kb (both dead after flash_attn)

  setup_kernel<<<4096, 256, 0, stream>>>(h, ln1g, ln1b, hn, adj, adjC,
                                         w_qkv, w_out, w1, w2,
                                         wqkvt, woutt, w1t, w2t);

  gemm128<0><<<dim3(12, 64), 256, 0, stream>>>(hn, wqkvt, b_qkv, nullptr,
                                               nullptr, nullptr, qb, kb, vt,
                                               NROW, 3 * DDIM, DDIM);

  flash_attn<<<dim3(16, 32), 256, 0, stream>>>(qb, kb, vt, adjC, attn);

  gemm64<1><<<dim3(4, 128), 256, 0, stream>>>(attn, woutt, b_out, h,
                                              out, nullptr, nullptr, nullptr, nullptr,
                                              NROW, DDIM, DDIM);

  ln_kernel<<<2048, 256, 0, stream>>>(out, ln2g, ln2b, ffin);

  gemm128<2><<<dim3(8, 64), 256, 0, stream>>>(ffin, w1t, b1, nullptr,
                                              nullptr, ffmid, nullptr, nullptr, nullptr,
                                              NROW, 2 * DDIM, DDIM);

  gemm64<1><<<dim3(4, 128), 256, 0, stream>>>(ffmid, w2t, b2, out,
                                              out, nullptr, nullptr, nullptr, nullptr,
                                              NROW, DDIM, 2 * DDIM);
}

// Round 14
// 181.822 us; speedup vs baseline: 2.2314x; 1.0579x over previous
//
#include <hip/hip_runtime.h>
#include <hip/hip_bf16.h>

// Problem constants
#define BDIM 4
#define CDIM 2048
#define DDIM 512
#define HH   8
#define DKH  64
#define NROW (BDIM * CDIM)   // 8192

typedef unsigned short u16;
typedef unsigned int   u32;
typedef u16   u16x4  __attribute__((ext_vector_type(4)));
typedef u16   u16x8  __attribute__((ext_vector_type(8)));
typedef u32   u32x4  __attribute__((ext_vector_type(4)));
typedef __bf16 bf16x8 __attribute__((ext_vector_type(8)));
typedef __bf16 bf16x2 __attribute__((ext_vector_type(2)));
typedef float f32x4  __attribute__((ext_vector_type(4)));
typedef float f32x16 __attribute__((ext_vector_type(16)));

#define LOG2E 1.4426950408889634f

__device__ __forceinline__ u16 f2bf(float f) {
  union { float f; unsigned u; } x; x.f = f;
  unsigned u = x.u;
  u += 0x7fffu + ((u >> 16) & 1u);   // RNE
  return (u16)(u >> 16);
}
__device__ __forceinline__ float bf2f(u16 u) {
  return __builtin_bit_cast(float, (u32)u << 16);
}
__device__ __forceinline__ u32 pk2(float a, float b) {
  bf16x2 t; t[0] = (__bf16)a; t[1] = (__bf16)b;
  return __builtin_bit_cast(u32, t);
}
__device__ __forceinline__ float fexp2(float x) {
  float r;
  asm("v_exp_f32 %0, %1" : "=v"(r) : "v"(x));  // inputs bounded; no libm fixup
  return r;
}

__device__ __forceinline__ void gload_lds16(const u16* gp, u16* lp) {
  // async global->LDS, 16B per lane; LDS dest is wave-uniform base + lane*16
  __builtin_amdgcn_global_load_lds((__attribute__((address_space(1))) const void*)gp,
                                   (__attribute__((address_space(3))) void*)lp, 16, 0, 0);
}

// ---------------- LayerNorm body: one wave per row of 512 ------------------
__device__ __forceinline__ void ln_body(int bx, int tid,
                                        const float* __restrict__ x,
                                        const float* __restrict__ gamma,
                                        const float* __restrict__ beta,
                                        u16* __restrict__ y) {
  int gw = (bx * 256 + tid) >> 6;
  int l  = tid & 63;
  const float* xr = x + (size_t)gw * DDIM;
  float4 a = *(const float4*)(xr + l * 8);
  float4 b = *(const float4*)(xr + l * 8 + 4);
  float s = a.x + a.y + a.z + a.w + b.x + b.y + b.z + b.w;
  float q = a.x*a.x + a.y*a.y + a.z*a.z + a.w*a.w + b.x*b.x + b.y*b.y + b.z*b.z + b.w*b.w;
#pragma unroll
  for (int m = 1; m < 64; m <<= 1) { s += __shfl_xor(s, m); q += __shfl_xor(q, m); }
  float mu  = s * (1.0f / DDIM);
  float var = q * (1.0f / DDIM) - mu * mu;
  float rs  = rsqrtf(var + 1e-5f);
  float4 g0 = *(const float4*)(gamma + l * 8);
  float4 g1 = *(const float4*)(gamma + l * 8 + 4);
  float4 b0 = *(const float4*)(beta + l * 8);
  float4 b1 = *(const float4*)(beta + l * 8 + 4);
  u16x8 o;
  o[0] = f2bf((a.x - mu) * rs * g0.x + b0.x);
  o[1] = f2bf((a.y - mu) * rs * g0.y + b0.y);
  o[2] = f2bf((a.z - mu) * rs * g0.z + b0.z);
  o[3] = f2bf((a.w - mu) * rs * g0.w + b0.w);
  o[4] = f2bf((b.x - mu) * rs * g1.x + b1.x);
  o[5] = f2bf((b.y - mu) * rs * g1.y + b1.y);
  o[6] = f2bf((b.z - mu) * rs * g1.z + b1.z);
  o[7] = f2bf((b.w - mu) * rs * g1.w + b1.w);
  *(u16x8*)(y + (size_t)gw * DDIM + l * 8) = o;
}

__global__ __launch_bounds__(256) void ln_kernel(const float* __restrict__ x,
                                                 const float* __restrict__ gamma,
                                                 const float* __restrict__ beta,
                                                 u16* __restrict__ y) {
  ln_body(blockIdx.x, threadIdx.x, x, gamma, beta, y);
}

// ---------------- adj transform body (one 1024-block-equivalent f) ---------
// adjC[b][kt][q][hi][32]: value v=m*16+a*4+c from adj[b][q][kt*64+m*32+a*8+hi*4+c]
__device__ __forceinline__ void adj_body(int f, int t,
                                         const float* __restrict__ adj,
                                         u16* __restrict__ adjC) {
  const int b = f >> 8, kt = (f >> 3) & 31;
  const int q0 = (f & 7) * 256;
  const int ch = t & 7, c16 = ch & 3, hi2 = ch >> 2, m = c16 >> 1;
  const int K0 = m * 32 + ((c16 * 2) & 3) * 8 + hi2 * 4;
#pragma unroll
  for (int itq = 0; itq < 8; ++itq) {
    int q = q0 + itq * 32 + (t >> 3);
    const float* src = adj + ((size_t)b * CDIM + q) * CDIM + kt * 64;
    f32x4 v0 = *(const f32x4*)(src + K0);
    f32x4 v1 = *(const f32x4*)(src + K0 + 8);
    u16x8 o;
    o[0] = f2bf(v0[0] * LOG2E); o[1] = f2bf(v0[1] * LOG2E);
    o[2] = f2bf(v0[2] * LOG2E); o[3] = f2bf(v0[3] * LOG2E);
    o[4] = f2bf(v1[0] * LOG2E); o[5] = f2bf(v1[1] * LOG2E);
    o[6] = f2bf(v1[2] * LOG2E); o[7] = f2bf(v1[3] * LOG2E);
    *(u16x8*)(adjC + ((size_t)(b * 32 + kt) * 2048 + q) * 64 + ch * 8) = o;
  }
}

// ---- setup1: ln1 (blocks 0-2047) + weight transpose (2048-3071) ------------
__global__ __launch_bounds__(256) void setup_kernel(const float* __restrict__ h,
                                                    const float* __restrict__ ln1g,
                                                    const float* __restrict__ ln1b,
                                                    u16* __restrict__ hn,
                                                    const float* __restrict__ wqkv,
                                                    const float* __restrict__ wout,
                                                    const float* __restrict__ w1,
                                                    const float* __restrict__ w2,
                                                    u16* __restrict__ o_qkv,
                                                    u16* __restrict__ o_out,
                                                    u16* __restrict__ o_w1,
                                                    u16* __restrict__ o_w2) {
  const int bx = blockIdx.x;
  const int t = threadIdx.x;
  if (bx < 2048) {
    ln_body(bx, t, h, ln1g, ln1b, hn);
  } else {
    int idx = (bx - 2048) * 256 + t;
    const float* w; u16* wt; int K, N;
    if (idx < 98304)       { w = wqkv; wt = o_qkv; K = 512;  N = 1536; }
    else if (idx < 131072) { idx -= 98304;  w = wout; wt = o_out; K = 512;  N = 512; }
    else if (idx < 196608) { idx -= 131072; w = w1;   wt = o_w1;  K = 512;  N = 1024; }
    else                   { idx -= 196608; w = w2;   wt = o_w2;  K = 1024; N = 512; }
    int kb = K >> 3;
    int n = idx / kb, k0 = (idx - n * kb) * 8;
    u16x8 o;
#pragma unroll
    for (int j = 0; j < 8; ++j) o[j] = f2bf(w[(size_t)(k0 + j) * N + n]);
    *(u16x8*)(wt + (size_t)n * K + k0) = o;
  }
}

// ------------- shared epilogue for GEMM tiles -------------------------------
template <int EPI>
__device__ __forceinline__ void gemm_epi(int row, int col, float val, int N,
                                         const float* __restrict__ res,
                                         float* __restrict__ outf,
                                         u16* __restrict__ outb,
                                         u16* __restrict__ outq,
                                         u16* __restrict__ outk,
                                         u16* __restrict__ outv) {
  if constexpr (EPI == 0) {
    int t = col >> 9, hh = (col >> 6) & 7, dk = col & 63;
    int bb = row >> 11, cc = row & 2047;
    if (t == 0) {
      val *= 0.125f * LOG2E;  // fold DK^-0.5 and log2(e) into q
      outq[(((size_t)bb * HH + hh) * CDIM + cc) * DKH + dk] = f2bf(val);
    } else if (t == 1) {
      outk[(((size_t)bb * HH + hh) * CDIM + cc) * DKH + dk] = f2bf(val);
    } else {  // V stored transposed: [bh][dk][C]
      outv[(((size_t)bb * HH + hh) * DKH + dk) * CDIM + cc] = f2bf(val);
    }
  } else if constexpr (EPI == 1) {
    size_t idx = (size_t)row * N + col;
    outf[idx] = val + res[idx];
  } else {
    float g = 0.5f * val * (1.0f + erff(val * 0.70710678118f));
    outb[(size_t)row * N + col] = f2bf(g);
  }
}

// ---------------- GEMM 128x128 body, BK=64, 4 waves (2x2 of 64x64) ----------
// XCD-bijective remap over (flat, nbn, nwg): each XCD owns a contiguous
// virt-chunk; consecutive virt share bm -> A-tiles L2-local (T1).
template <int EPI>
__device__ __forceinline__ void gemm128_body(int flat, int nbn, int nwg,
                                             const u16* __restrict__ A,
                                             const u16* __restrict__ Bt,
                                             const float* __restrict__ bias,
                                             const float* __restrict__ res,
                                             float* __restrict__ outf,
                                             u16* __restrict__ outb,
                                             u16* __restrict__ outq,
                                             u16* __restrict__ outk,
                                             u16* __restrict__ outv,
                                             int N, int K) {
  __shared__ u16 As[2][128 * 64];
  __shared__ u16 Bs[2][128 * 64];
  const int tid = threadIdx.x;
  const int w = tid >> 6, l = tid & 63;
  const int l15 = l & 15, l4 = l >> 4, l7 = l15 & 7;
  const int virt = (flat & 7) * (nwg >> 3) + (flat >> 3);
  const int bn = virt % nbn, bm = virt / nbn;
  const int wr = w >> 1, wc = w & 1;

  f32x4 acc[4][4] = {};

  const int sg = (l & 7) ^ (l >> 3);   // pre-swizzled source granule
  const u16* Ag = A  + (size_t)(bm * 128 + w * 32 + (l >> 3)) * K + sg * 8;
  const u16* Bg = Bt + (size_t)(bn * 128 + w * 32 + (l >> 3)) * K + sg * 8;

  auto stage = [&](int buf, int k0) {
#pragma unroll
    for (int i = 0; i < 4; ++i) {
      gload_lds16(Ag + (size_t)(8 * i) * K + k0, &As[buf][(w * 32 + 8 * i) * 64]);
      gload_lds16(Bg + (size_t)(8 * i) * K + k0, &Bs[buf][(w * 32 + 8 * i) * 64]);
    }
  };

  stage(0, 0);
  __syncthreads();
  int cur = 0;
  for (int k0 = 0; k0 < K; k0 += 64) {
    if (k0 + 64 < K) stage(cur ^ 1, k0 + 64);
#pragma unroll
    for (int s = 0; s < 2; ++s) {
      bf16x8 af[4], bf[4];
#pragma unroll
      for (int m = 0; m < 4; ++m)
        af[m] = *(const bf16x8*)(&As[cur][(wr * 64 + m * 16 + l15) * 64 + (((s * 4 + l4) ^ l7) * 8)]);
#pragma unroll
      for (int n = 0; n < 4; ++n)
        bf[n] = *(const bf16x8*)(&Bs[cur][(wc * 64 + n * 16 + l15) * 64 + (((s * 4 + l4) ^ l7) * 8)]);
#pragma unroll
      for (int m = 0; m < 4; ++m)
#pragma unroll
        for (int n = 0; n < 4; ++n)
          acc[m][n] = __builtin_amdgcn_mfma_f32_16x16x32_bf16(af[m], bf[n], acc[m][n], 0, 0, 0);
    }
    __syncthreads();
    cur ^= 1;
  }

#pragma unroll
  for (int m = 0; m < 4; ++m) {
    const int row0 = bm * 128 + wr * 64 + m * 16 + l4 * 4;
#pragma unroll
    for (int n = 0; n < 4; ++n) {
      const int col = bn * 128 + wc * 64 + n * 16 + l15;
      const float bv = bias[col];
#pragma unroll
      for (int r = 0; r < 4; ++r)
        gemm_epi<EPI>(row0 + r, col, acc[m][n][r] + bv, N, res, outf, outb, outq, outk, outv);
    }
  }
}

// ---- fused: qkv GEMM (blocks 0-767) + adj transform (768-1791) -------------
// The GEMM is L2/MFMA-bound, the transform pure-HBM -> co-residency overlaps
// the two instead of serializing ~17us of adj streaming.
__global__ __launch_bounds__(256) void qkv_adj_kernel(const u16* __restrict__ A,
                                                      const u16* __restrict__ Bt,
                                                      const float* __restrict__ bias,
                                                      u16* __restrict__ outq,
                                                      u16* __restrict__ outk,
                                                      u16* __restrict__ outv,
                                                      const float* __restrict__ adj,
                                                      u16* __restrict__ adjC) {
  if (blockIdx.x < 768) {
    gemm128_body<0>(blockIdx.x, 12, 768, A, Bt, bias, nullptr,
                    nullptr, nullptr, outq, outk, outv, 3 * DDIM, DDIM);
  } else {
    adj_body(blockIdx.x - 768, threadIdx.x, adj, adjC);
  }
}

// ---------------- standalone gemm128 (ff1) ----------------------------------
template <int EPI>
__global__ __launch_bounds__(256) void gemm128k(const u16* __restrict__ A,
                                                const u16* __restrict__ Bt,
                                                const float* __restrict__ bias,
                                                const float* __restrict__ res,
                                                float* __restrict__ outf,
                                                u16* __restrict__ outb,
                                                int M, int N, int K) {
  gemm128_body<EPI>(blockIdx.x + gridDim.x * blockIdx.y, gridDim.x,
                    gridDim.x * gridDim.y, A, Bt, bias, res,
                    outf, outb, nullptr, nullptr, nullptr, N, K);
}

// ---------------- GEMM 64x128, BK=64, 4 waves -------------------------------
template <int EPI>
__global__ __launch_bounds__(256) void gemm64(const u16* __restrict__ A,
                                              const u16* __restrict__ Bt,
                                              const float* __restrict__ bias,
                                              const float* __restrict__ res,
                                              float* __restrict__ outf,
                                              u16* __restrict__ outb,
                                              int M, int N, int K) {
  __shared__ u16 As[2][64 * 64];
  __shared__ u16 Bs[2][128 * 64];
  const int tid = threadIdx.x;
  const int w = tid >> 6, l = tid & 63;
  const int l15 = l & 15, l4 = l >> 4, l7 = l15 & 7;
  const int nbn = gridDim.x, nwg = gridDim.x * gridDim.y;
  const int flat = blockIdx.x + nbn * blockIdx.y;
  const int virt = (flat & 7) * (nwg >> 3) + (flat >> 3);
  const int bn = virt % nbn, bm = virt / nbn;

  f32x4 acc[4][2] = {};

  const int sg = (l & 7) ^ (l >> 3);   // pre-swizzled source granule
  const u16* Ag = A  + (size_t)(bm * 64  + w * 16 + (l >> 3)) * K + sg * 8;
  const u16* Bg = Bt + (size_t)(bn * 128 + w * 32 + (l >> 3)) * K + sg * 8;

  auto stage = [&](int buf, int k0) {
    gload_lds16(Ag + k0,                  &As[buf][(w * 16 + 0) * 64]);
    gload_lds16(Ag + (size_t)8 * K + k0,  &As[buf][(w * 16 + 8) * 64]);
    gload_lds16(Bg + k0,                  &Bs[buf][(w * 32 + 0) * 64]);
    gload_lds16(Bg + (size_t)8 * K + k0,  &Bs[buf][(w * 32 + 8) * 64]);
    gload_lds16(Bg + (size_t)16 * K + k0, &Bs[buf][(w * 32 + 16) * 64]);
    gload_lds16(Bg + (size_t)24 * K + k0, &Bs[buf][(w * 32 + 24) * 64]);
  };

  stage(0, 0);
  __syncthreads();
  int cur = 0;
  for (int k0 = 0; k0 < K; k0 += 64) {
    if (k0 + 64 < K) stage(cur ^ 1, k0 + 64);
#pragma unroll
    for (int s = 0; s < 2; ++s) {
      bf16x8 af[4], bf[2];
#pragma unroll
      for (int m = 0; m < 4; ++m)
        af[m] = *(const bf16x8*)(&As[cur][(m * 16 + l15) * 64 + (((s * 4 + l4) ^ l7) * 8)]);
#pragma unroll
      for (int n = 0; n < 2; ++n)
        bf[n] = *(const bf16x8*)(&Bs[cur][(w * 32 + n * 16 + l15) * 64 + (((s * 4 + l4) ^ l7) * 8)]);
#pragma unroll
      for (int m = 0; m < 4; ++m)
#pragma unroll
        for (int n = 0; n < 2; ++n)
          acc[m][n] = __builtin_amdgcn_mfma_f32_16x16x32_bf16(af[m], bf[n], acc[m][n], 0, 0, 0);
    }
    __syncthreads();
    cur ^= 1;
  }

#pragma unroll
  for (int m = 0; m < 4; ++m) {
    const int row0 = bm * 64 + m * 16 + l4 * 4;
#pragma unroll
    for (int n = 0; n < 2; ++n) {
      const int col = bn * 128 + w * 32 + n * 16 + l15;
      const float bv = bias[col];
#pragma unroll
      for (int r = 0; r < 4; ++r)
        gemm_epi<EPI>(row0 + r, col, acc[m][n][r] + bv, N, res, outf, outb,
                      nullptr, nullptr, nullptr);
    }
  }
}

// ---------------- flash attention: split-kt, 32x32 swapped-QK^T -------------
// R11 structure (best measured: 65.6us, VGPR 96): 512 threads = 8 warps =
// 4 q-subtiles (qg) x 2 kt-halves (kh); (512,2) -> 128 VGPR cap, 16 waves/CU.
__global__ __launch_bounds__(512, 2) void flash_attn(const u16* __restrict__ Q,
                                                     const u16* __restrict__ Kg,
                                                     const u16* __restrict__ Vt,
                                                     const u16* __restrict__ adjC,
                                                     u16* __restrict__ O) {
  __shared__ u16 Ks[2][2][64 * 64];   // [kh][buf]
  __shared__ u16 Vs[2][2][64 * 64];
  __shared__ float lw[4][32];
  __shared__ float lsx[4][32];
  const int flat = blockIdx.x + 16 * blockIdx.y;       // 512 blocks
  const int virt = (flat & 7) * 64 + (flat >> 3);      // XCD-contiguous remap
  const int qt = virt & 15;
  const int bh = virt >> 4;
  const int b = bh >> 3, hh = bh & 7;
  const int tid = threadIdx.x;
  const int w = tid >> 6, l = tid & 63;
  const int kh = w >> 2, qg = w & 3;
  const int q32 = l & 31, hi = l >> 5;
  const int qglob = qt * 128 + qg * 32 + q32;

  const u16* Qb = Q  + (size_t)bh * CDIM * DKH;
  const u16* Kb = Kg + (size_t)bh * CDIM * DKH;
  const u16* Vb = Vt + (size_t)bh * DKH * CDIM;  // [dk][C]

  const int srow = qg * 16 + (l >> 3);
  const int sg   = (l & 7) ^ (l >> 3);  // pre-swizzled source granule
  const u16* Kg0 = Kb + (size_t)(srow + 0) * DKH + sg * 8;
  const u16* Kg1 = Kb + (size_t)(srow + 8) * DKH + sg * 8;
  const u16* Vg0 = Vb + (size_t)(srow + 0) * CDIM + sg * 8;
  const u16* Vg1 = Vb + (size_t)(srow + 8) * CDIM + sg * 8;

  bf16x8 qf[4];
#pragma unroll
  for (int s = 0; s < 4; ++s)
    qf[s] = *(const bf16x8*)(Qb + (size_t)qglob * DKH + s * 16 + hi * 8);

  const u16* adjQ = adjC + ((size_t)(b * 32) * 2048 + qglob) * 64 + hi * 32;

  f32x16 oa[2] = {};
  float lsum = 0.f;

  auto stage = [&](int buf, int ktr) {
    int kta = kh * 16 + ktr;
    gload_lds16(Kg0 + (size_t)kta * 4096, &Ks[kh][buf][(qg * 16 + 0) * 64]);
    gload_lds16(Kg1 + (size_t)kta * 4096, &Ks[kh][buf][(qg * 16 + 8) * 64]);
    gload_lds16(Vg0 + kta * 64, &Vs[kh][buf][(qg * 16 + 0) * 64]);
    gload_lds16(Vg1 + kta * 64, &Vs[kh][buf][(qg * 16 + 8) * 64]);
  };
  auto ajload = [&](u16x8* dst, int ktr) {
    const u16* p = adjQ + (size_t)(kh * 16 + ktr) * 131072;  // 2048*64 u16 per kt
#pragma unroll
    for (int i = 0; i < 4; ++i) dst[i] = *(const u16x8*)(p + i * 8);
  };
  auto computeQK = [&](const u16* KsB, const u16x8* av, f32x16* sa) {
#pragma unroll
    for (int m = 0; m < 2; ++m)
#pragma unroll
      for (int r = 0; r < 16; ++r)
        sa[m][r] = bf2f(av[m * 2 + (r >> 3)][r & 7]);
    __builtin_amdgcn_s_setprio(1);
#pragma unroll
    for (int s = 0; s < 4; ++s)
#pragma unroll
      for (int m = 0; m < 2; ++m) {
        bf16x8 kf = *(const bf16x8*)(&KsB[(m * 32 + q32) * 64 + (((s * 2 + hi) ^ (q32 & 7)) * 8)]);
        sa[m] = __builtin_amdgcn_mfma_f32_32x32x16_bf16(kf, qf[s], sa[m], 0, 0, 0);
      }
    __builtin_amdgcn_s_setprio(0);
  };
  auto computePV = [&](const u16* VsB, f32x16* sa) {
#pragma unroll
    for (int m = 0; m < 2; ++m)
#pragma unroll
      for (int r = 0; r < 16; ++r) {
        float p = fexp2(sa[m][r]);
        sa[m][r] = p;
        lsum += p;
      }
    bf16x8 af[4];
#pragma unroll
    for (int m = 0; m < 2; ++m)
#pragma unroll
      for (int t2 = 0; t2 < 2; ++t2) {
        u32 w0 = pk2(sa[m][t2 * 8 + 0], sa[m][t2 * 8 + 1]);
        u32 w1 = pk2(sa[m][t2 * 8 + 2], sa[m][t2 * 8 + 3]);
        u32 w2 = pk2(sa[m][t2 * 8 + 4], sa[m][t2 * 8 + 5]);
        u32 w3 = pk2(sa[m][t2 * 8 + 6], sa[m][t2 * 8 + 7]);
        auto r02 = __builtin_amdgcn_permlane32_swap(w0, w2, false, false);
        auto r13 = __builtin_amdgcn_permlane32_swap(w1, w3, false, false);
        u32x4 aw;
        aw[0] = r02[0];
        aw[1] = r13[0];
        aw[2] = r02[1];
        aw[3] = r13[1];
        af[m * 2 + t2] = __builtin_bit_cast(bf16x8, aw);
      }
    __builtin_amdgcn_s_setprio(1);
#pragma unroll
    for (int s = 0; s < 4; ++s)
#pragma unroll
      for (int n = 0; n < 2; ++n) {
        bf16x8 vf = *(const bf16x8*)(&VsB[(n * 32 + q32) * 64 + (((s * 2 + hi) ^ (q32 & 7)) * 8)]);
        oa[n] = __builtin_amdgcn_mfma_f32_32x32x16_bf16(af[s], vf, oa[n], 0, 0, 0);
      }
    __builtin_amdgcn_s_setprio(0);
  };

  u16x8 avA[4], avB[4];
  f32x16 sa[2];
  stage(0, 0);
  ajload(avA, 0);
  __syncthreads();
#pragma unroll 1
  for (int it = 0; it < 8; ++it) {
    int ktr = it * 2;
    stage(1, ktr + 1);
    computeQK(&Ks[kh][0][0], avA, sa);
    ajload(avB, ktr + 1);           // prefetch next adj under PV
    computePV(&Vs[kh][0][0], sa);
    __syncthreads();
    if (ktr + 2 < 16) stage(0, ktr + 2);
    computeQK(&Ks[kh][1][0], avB, sa);
    if (ktr + 2 < 16) ajload(avA, ktr + 2);
    computePV(&Vs[kh][1][0], sa);
    __syncthreads();
  }

  // lane + partner(l^32) hold complementary k-halves of this kh's range
  lsum += __shfl_xor(lsum, 32);

  // combine kh halves through LDS (K/V buffers are dead now)
  float* cb = (float*)&Vs[0][0][0];   // 32KB: exactly the Vs space
  if (kh == 1) {
#pragma unroll
    for (int n = 0; n < 2; ++n)
#pragma unroll
      for (int r = 0; r < 16; ++r)
        cb[((qg * 2 + n) * 16 + r) * 64 + l] = oa[n][r];
    if (hi == 0) lsx[qg][q32] = lsum;
  }
  __syncthreads();
  if (kh == 0) {
    lsum += lsx[qg][q32];
#pragma unroll
    for (int n = 0; n < 2; ++n)
#pragma unroll
      for (int r = 0; r < 16; ++r)
        oa[n][r] += cb[((qg * 2 + n) * 16 + r) * 64 + l];
    lw[qg][q32] = 1.0f / lsum;
    // write attn_out: row-major [8192][512] bf16, col offset hh*64
#pragma unroll
    for (int n = 0; n < 2; ++n)
#pragma unroll
      for (int r = 0; r < 16; ++r) {
        int qloc = (r & 3) + 8 * (r >> 2) + 4 * hi;
        int row = qt * 128 + qg * 32 + qloc;
        float val = oa[n][r] * lw[qg][qloc];
        O[((size_t)b * CDIM + row) * DDIM + hh * 64 + n * 32 + q32] = f2bf(val);
      }
  }
}

extern "C" void kernel_launch(void* const* d_in, const int* in_sizes, int n_in,
                              void* d_out, int out_size, void* d_ws, size_t ws_size,
                              hipStream_t stream) {
  const float* h      = (const float*)d_in[0];
  const float* adj    = (const float*)d_in[1];
  const float* w_qkv  = (const float*)d_in[2];
  const float* b_qkv  = (const float*)d_in[3];
  const float* w_out  = (const float*)d_in[4];
  const float* b_out  = (const float*)d_in[5];
  const float* ln1g   = (const float*)d_in[6];
  const float* ln1b   = (const float*)d_in[7];
  const float* ln2g   = (const float*)d_in[8];
  const float* ln2b   = (const float*)d_in[9];
  const float* w1     = (const float*)d_in[10];
  const float* b1     = (const float*)d_in[11];
  const float* w2     = (const float*)d_in[12];
  const float* b2     = (const float*)d_in[13];
  float* out = (float*)d_out;

  char* ws = (char*)d_ws;
  u16* adjC  = (u16*)(ws);                      // 32 MiB exactly, dead after flash
  u16* hn    = (u16*)(ws + 33554432);           // 8 MiB; reused as ff_in
  u16* qb    = (u16*)(ws + 41943040);           // q head-major; later ffmid spans qb+kb
  u16* kb    = (u16*)(ws + 50331648);
  u16* vt    = (u16*)(ws + 58720256);           // V transposed [bh][dk][C]
  u16* attn  = (u16*)(ws + 67108864);
  u16* wqkvt = (u16*)(ws + 75497472);           // 1536x512 bf16 = 1.5MiB
  u16* woutt = (u16*)(ws + 77070336);           // 512x512
  u16* w1t   = (u16*)(ws + 77594624);           // 1024x512
  u16* w2t   = (u16*)(ws + 78643200);           // 512x1024
  u16* ffin  = hn;
  u16* ffmid = qb;   // 16MiB spans qb+kb (both dead after flash_attn)

  setup_kernel<<<3072, 256, 0, stream>>>(h, ln1g, ln1b, hn,
                                         w_qkv, w_out, w1, w2,
                                         wqkvt, woutt, w1t, w2t);

  qkv_adj_kernel<<<1792, 256, 0, stream>>>(hn, wqkvt, b_qkv, qb, kb, vt,
                                           adj, adjC);

  flash_attn<<<dim3(16, 32), 512, 0, stream>>>(qb, kb, vt, adjC, attn);

  gemm64<1><<<dim3(4, 128), 256, 0, stream>>>(attn, woutt, b_out, h,
                                              out, nullptr, NROW, DDIM, DDIM);

  ln_kernel<<<2048, 256, 0, stream>>>(out, ln2g, ln2b, ffin);

  gemm128k<2><<<dim3(8, 64), 256, 0, stream>>>(ffin, w1t, b1, nullptr,
                                               nullptr, ffmid, NROW, 2 * DDIM, DDIM);

  gemm64<1><<<dim3(4, 128), 256, 0, stream>>>(ffmid, w2t, b2, out,
                                              out, nullptr, NROW, DDIM, 2 * DDIM);
}

// Round 15
// 176.689 us; speedup vs baseline: 2.2962x; 1.0291x over previous
//
#include <hip/hip_runtime.h>
#include <hip/hip_bf16.h>

// Problem constants
#define BDIM 4
#define CDIM 2048
#define DDIM 512
#define HH   8
#define DKH  64
#define NROW (BDIM * CDIM)   // 8192

typedef unsigned short u16;
typedef unsigned int   u32;
typedef u16   u16x4  __attribute__((ext_vector_type(4)));
typedef u16   u16x8  __attribute__((ext_vector_type(8)));
typedef u32   u32x4  __attribute__((ext_vector_type(4)));
typedef __bf16 bf16x8 __attribute__((ext_vector_type(8)));
typedef __bf16 bf16x2 __attribute__((ext_vector_type(2)));
typedef float f32x4  __attribute__((ext_vector_type(4)));
typedef float f32x16 __attribute__((ext_vector_type(16)));

#define LOG2E 1.4426950408889634f

// compiler-fenced raw barrier + counted vmcnt (T3/T4)
#define MEMFENCE asm volatile("" ::: "memory")
__device__ __forceinline__ void sbar() {
  MEMFENCE; __builtin_amdgcn_s_barrier(); MEMFENCE;
}
#define VMWAIT(N) asm volatile("s_waitcnt vmcnt(" #N ")" ::: "memory")

__device__ __forceinline__ u16 f2bf(float f) {
  union { float f; unsigned u; } x; x.f = f;
  unsigned u = x.u;
  u += 0x7fffu + ((u >> 16) & 1u);   // RNE
  return (u16)(u >> 16);
}
__device__ __forceinline__ float bf2f(u16 u) {
  return __builtin_bit_cast(float, (u32)u << 16);
}
__device__ __forceinline__ u32 pk2(float a, float b) {
  bf16x2 t; t[0] = (__bf16)a; t[1] = (__bf16)b;
  return __builtin_bit_cast(u32, t);
}
__device__ __forceinline__ float fexp2(float x) {
  float r;
  asm("v_exp_f32 %0, %1" : "=v"(r) : "v"(x));  // inputs bounded; no libm fixup
  return r;
}

__device__ __forceinline__ void gload_lds16(const u16* gp, u16* lp) {
  // async global->LDS, 16B per lane; LDS dest is wave-uniform base + lane*16
  __builtin_amdgcn_global_load_lds((__attribute__((address_space(1))) const void*)gp,
                                   (__attribute__((address_space(3))) void*)lp, 16, 0, 0);
}

// ---------------- LayerNorm body: one wave per row of 512 ------------------
__device__ __forceinline__ void ln_body(int bx, int tid,
                                        const float* __restrict__ x,
                                        const float* __restrict__ gamma,
                                        const float* __restrict__ beta,
                                        u16* __restrict__ y) {
  int gw = (bx * 256 + tid) >> 6;
  int l  = tid & 63;
  const float* xr = x + (size_t)gw * DDIM;
  float4 a = *(const float4*)(xr + l * 8);
  float4 b = *(const float4*)(xr + l * 8 + 4);
  float s = a.x + a.y + a.z + a.w + b.x + b.y + b.z + b.w;
  float q = a.x*a.x + a.y*a.y + a.z*a.z + a.w*a.w + b.x*b.x + b.y*b.y + b.z*b.z + b.w*b.w;
#pragma unroll
  for (int m = 1; m < 64; m <<= 1) { s += __shfl_xor(s, m); q += __shfl_xor(q, m); }
  float mu  = s * (1.0f / DDIM);
  float var = q * (1.0f / DDIM) - mu * mu;
  float rs  = rsqrtf(var + 1e-5f);
  float4 g0 = *(const float4*)(gamma + l * 8);
  float4 g1 = *(const float4*)(gamma + l * 8 + 4);
  float4 b0 = *(const float4*)(beta + l * 8);
  float4 b1 = *(const float4*)(beta + l * 8 + 4);
  u16x8 o;
  o[0] = f2bf((a.x - mu) * rs * g0.x + b0.x);
  o[1] = f2bf((a.y - mu) * rs * g0.y + b0.y);
  o[2] = f2bf((a.z - mu) * rs * g0.z + b0.z);
  o[3] = f2bf((a.w - mu) * rs * g0.w + b0.w);
  o[4] = f2bf((b.x - mu) * rs * g1.x + b1.x);
  o[5] = f2bf((b.y - mu) * rs * g1.y + b1.y);
  o[6] = f2bf((b.z - mu) * rs * g1.z + b1.z);
  o[7] = f2bf((b.w - mu) * rs * g1.w + b1.w);
  *(u16x8*)(y + (size_t)gw * DDIM + l * 8) = o;
}

__global__ __launch_bounds__(256) void ln_kernel(const float* __restrict__ x,
                                                 const float* __restrict__ gamma,
                                                 const float* __restrict__ beta,
                                                 u16* __restrict__ y) {
  ln_body(blockIdx.x, threadIdx.x, x, gamma, beta, y);
}

// ---------------- adj transform body (one 1024-block-equivalent f) ---------
// adjC[b][kt][q][hi][32]: value v=m*16+a*4+c from adj[b][q][kt*64+m*32+a*8+hi*4+c]
__device__ __forceinline__ void adj_body(int f, int t,
                                         const float* __restrict__ adj,
                                         u16* __restrict__ adjC) {
  const int b = f >> 8, kt = (f >> 3) & 31;
  const int q0 = (f & 7) * 256;
  const int ch = t & 7, c16 = ch & 3, hi2 = ch >> 2, m = c16 >> 1;
  const int K0 = m * 32 + ((c16 * 2) & 3) * 8 + hi2 * 4;
#pragma unroll
  for (int itq = 0; itq < 8; ++itq) {
    int q = q0 + itq * 32 + (t >> 3);
    const float* src = adj + ((size_t)b * CDIM + q) * CDIM + kt * 64;
    f32x4 v0 = *(const f32x4*)(src + K0);
    f32x4 v1 = *(const f32x4*)(src + K0 + 8);
    u16x8 o;
    o[0] = f2bf(v0[0] * LOG2E); o[1] = f2bf(v0[1] * LOG2E);
    o[2] = f2bf(v0[2] * LOG2E); o[3] = f2bf(v0[3] * LOG2E);
    o[4] = f2bf(v1[0] * LOG2E); o[5] = f2bf(v1[1] * LOG2E);
    o[6] = f2bf(v1[2] * LOG2E); o[7] = f2bf(v1[3] * LOG2E);
    *(u16x8*)(adjC + ((size_t)(b * 32 + kt) * 2048 + q) * 64 + ch * 8) = o;
  }
}

// ---- setup1: ln1 (blocks 0-2047) + weight transpose (2048-3071) ------------
__global__ __launch_bounds__(256) void setup_kernel(const float* __restrict__ h,
                                                    const float* __restrict__ ln1g,
                                                    const float* __restrict__ ln1b,
                                                    u16* __restrict__ hn,
                                                    const float* __restrict__ wqkv,
                                                    const float* __restrict__ wout,
                                                    const float* __restrict__ w1,
                                                    const float* __restrict__ w2,
                                                    u16* __restrict__ o_qkv,
                                                    u16* __restrict__ o_out,
                                                    u16* __restrict__ o_w1,
                                                    u16* __restrict__ o_w2) {
  const int bx = blockIdx.x;
  const int t = threadIdx.x;
  if (bx < 2048) {
    ln_body(bx, t, h, ln1g, ln1b, hn);
  } else {
    int idx = (bx - 2048) * 256 + t;
    const float* w; u16* wt; int K, N;
    if (idx < 98304)       { w = wqkv; wt = o_qkv; K = 512;  N = 1536; }
    else if (idx < 131072) { idx -= 98304;  w = wout; wt = o_out; K = 512;  N = 512; }
    else if (idx < 196608) { idx -= 131072; w = w1;   wt = o_w1;  K = 512;  N = 1024; }
    else                   { idx -= 196608; w = w2;   wt = o_w2;  K = 1024; N = 512; }
    int kb = K >> 3;
    int n = idx / kb, k0 = (idx - n * kb) * 8;
    u16x8 o;
#pragma unroll
    for (int j = 0; j < 8; ++j) o[j] = f2bf(w[(size_t)(k0 + j) * N + n]);
    *(u16x8*)(wt + (size_t)n * K + k0) = o;
  }
}

// ------------- shared epilogue for GEMM tiles -------------------------------
template <int EPI>
__device__ __forceinline__ void gemm_epi(int row, int col, float val, int N,
                                         const float* __restrict__ res,
                                         float* __restrict__ outf,
                                         u16* __restrict__ outb,
                                         u16* __restrict__ outq,
                                         u16* __restrict__ outk,
                                         u16* __restrict__ outv) {
  if constexpr (EPI == 0) {
    int t = col >> 9, hh = (col >> 6) & 7, dk = col & 63;
    int bb = row >> 11, cc = row & 2047;
    if (t == 0) {
      val *= 0.125f * LOG2E;  // fold DK^-0.5 and log2(e) into q
      outq[(((size_t)bb * HH + hh) * CDIM + cc) * DKH + dk] = f2bf(val);
    } else if (t == 1) {
      outk[(((size_t)bb * HH + hh) * CDIM + cc) * DKH + dk] = f2bf(val);
    } else {  // V stored transposed: [bh][dk][C]
      outv[(((size_t)bb * HH + hh) * DKH + dk) * CDIM + cc] = f2bf(val);
    }
  } else if constexpr (EPI == 1) {
    size_t idx = (size_t)row * N + col;
    outf[idx] = val + res[idx];
  } else {
    float g = 0.5f * val * (1.0f + erff(val * 0.70710678118f));
    outb[(size_t)row * N + col] = f2bf(g);
  }
}

// ---------------- GEMM 128x128 body, BK=32, 3-buffer counted-vmcnt ----------
// Single barrier per K-step: stage(i+1) at top -> vmcnt(4) waits ONLY tile i
// (tile i+1's 4 loads stay in flight ACROSS the barrier, landing under
// compute) -> s_barrier -> compute(i). Buffer safety: stage(i+1) overwrites
// the buffer last read in compute(i-2); every wave has passed the iter-(i-1)
// barrier (which precedes compute(i-1)), so compute(i-2) is globally done.
// LDS 48KB -> 3 blocks/CU. XOR-granule swizzle re-derived for BK=32:
// read granule l4^(row&3) -> 2-way bank alias (free); source pre-swizzled.
template <int EPI>
__device__ __forceinline__ void gemm128_body(int flat, int nbn, int nwg,
                                             const u16* __restrict__ A,
                                             const u16* __restrict__ Bt,
                                             const float* __restrict__ bias,
                                             const float* __restrict__ res,
                                             float* __restrict__ outf,
                                             u16* __restrict__ outb,
                                             u16* __restrict__ outq,
                                             u16* __restrict__ outk,
                                             u16* __restrict__ outv,
                                             int N, int K) {
  __shared__ u16 As[3][128 * 32];
  __shared__ u16 Bs[3][128 * 32];
  const int tid = threadIdx.x;
  const int w = tid >> 6, l = tid & 63;
  const int l15 = l & 15, l4 = l >> 4;
  const int virt = (flat & 7) * (nwg >> 3) + (flat >> 3);
  const int bn = virt % nbn, bm = virt / nbn;
  const int wr = w >> 1, wc = w & 1;

  f32x4 acc[4][4] = {};

  // staging: wave w covers rows [w*32, w*32+32); lane: row +(l>>2), granule
  // (l&3)^((l>>2)&3) pre-swizzled (8 u16 = 16B granules, 4 per 32-col row)
  const int sg = (l & 3) ^ ((l >> 2) & 3);
  const u16* Ag = A  + (size_t)(bm * 128 + w * 32 + (l >> 2)) * K + sg * 8;
  const u16* Bg = Bt + (size_t)(bn * 128 + w * 32 + (l >> 2)) * K + sg * 8;

  auto stage = [&](int buf, int k0) {
    gload_lds16(Ag + k0,                  &As[buf][(w * 32 + 0) * 32]);
    gload_lds16(Ag + (size_t)16 * K + k0, &As[buf][(w * 32 + 16) * 32]);
    gload_lds16(Bg + k0,                  &Bs[buf][(w * 32 + 0) * 32]);
    gload_lds16(Bg + (size_t)16 * K + k0, &Bs[buf][(w * 32 + 16) * 32]);
  };

  const int nk = K >> 5;
  stage(0, 0);
  int bcur = 0, bnxt = 1;
#pragma unroll 1
  for (int i = 0; i < nk; ++i) {
    if (i + 1 < nk) {
      stage(bnxt, (i + 1) * 32);
      VMWAIT(4);                 // tile i landed; tile i+1 in flight
    } else {
      VMWAIT(0);                 // last tile: drain
    }
    sbar();
    const u16* AsC = &As[bcur][0];
    const u16* BsC = &Bs[bcur][0];
    bf16x8 af[4], bf[4];
#pragma unroll
    for (int m = 0; m < 4; ++m)
      af[m] = *(const bf16x8*)(&AsC[(wr * 64 + m * 16 + l15) * 32 + ((l4 ^ (l15 & 3)) * 8)]);
#pragma unroll
    for (int n = 0; n < 4; ++n)
      bf[n] = *(const bf16x8*)(&BsC[(wc * 64 + n * 16 + l15) * 32 + ((l4 ^ (l15 & 3)) * 8)]);
#pragma unroll
    for (int m = 0; m < 4; ++m)
#pragma unroll
      for (int n = 0; n < 4; ++n)
        acc[m][n] = __builtin_amdgcn_mfma_f32_16x16x32_bf16(af[m], bf[n], acc[m][n], 0, 0, 0);
    bcur = bnxt;
    bnxt = bnxt + 1 == 3 ? 0 : bnxt + 1;
  }

#pragma unroll
  for (int m = 0; m < 4; ++m) {
    const int row0 = bm * 128 + wr * 64 + m * 16 + l4 * 4;
#pragma unroll
    for (int n = 0; n < 4; ++n) {
      const int col = bn * 128 + wc * 64 + n * 16 + l15;
      const float bv = bias[col];
#pragma unroll
      for (int r = 0; r < 4; ++r)
        gemm_epi<EPI>(row0 + r, col, acc[m][n][r] + bv, N, res, outf, outb, outq, outk, outv);
    }
  }
}

// ---- fused: qkv GEMM (blocks 0-767) + adj transform (768-1791) -------------
__global__ __launch_bounds__(256) void qkv_adj_kernel(const u16* __restrict__ A,
                                                      const u16* __restrict__ Bt,
                                                      const float* __restrict__ bias,
                                                      u16* __restrict__ outq,
                                                      u16* __restrict__ outk,
                                                      u16* __restrict__ outv,
                                                      const float* __restrict__ adj,
                                                      u16* __restrict__ adjC) {
  if (blockIdx.x < 768) {
    gemm128_body<0>(blockIdx.x, 12, 768, A, Bt, bias, nullptr,
                    nullptr, nullptr, outq, outk, outv, 3 * DDIM, DDIM);
  } else {
    adj_body(blockIdx.x - 768, threadIdx.x, adj, adjC);
  }
}

// ---------------- standalone gemm128 (ff1) ----------------------------------
template <int EPI>
__global__ __launch_bounds__(256) void gemm128k(const u16* __restrict__ A,
                                                const u16* __restrict__ Bt,
                                                const float* __restrict__ bias,
                                                const float* __restrict__ res,
                                                float* __restrict__ outf,
                                                u16* __restrict__ outb,
                                                int M, int N, int K) {
  gemm128_body<EPI>(blockIdx.x + gridDim.x * blockIdx.y, gridDim.x,
                    gridDim.x * gridDim.y, A, Bt, bias, res,
                    outf, outb, nullptr, nullptr, nullptr, N, K);
}

// ---------------- GEMM 64x128, BK=64, 4 waves (unchanged control) -----------
template <int EPI>
__global__ __launch_bounds__(256) void gemm64(const u16* __restrict__ A,
                                              const u16* __restrict__ Bt,
                                              const float* __restrict__ bias,
                                              const float* __restrict__ res,
                                              float* __restrict__ outf,
                                              u16* __restrict__ outb,
                                              int M, int N, int K) {
  __shared__ u16 As[2][64 * 64];
  __shared__ u16 Bs[2][128 * 64];
  const int tid = threadIdx.x;
  const int w = tid >> 6, l = tid & 63;
  const int l15 = l & 15, l4 = l >> 4, l7 = l15 & 7;
  const int nbn = gridDim.x, nwg = gridDim.x * gridDim.y;
  const int flat = blockIdx.x + nbn * blockIdx.y;
  const int virt = (flat & 7) * (nwg >> 3) + (flat >> 3);
  const int bn = virt % nbn, bm = virt / nbn;

  f32x4 acc[4][2] = {};

  const int sg = (l & 7) ^ (l >> 3);   // pre-swizzled source granule
  const u16* Ag = A  + (size_t)(bm * 64  + w * 16 + (l >> 3)) * K + sg * 8;
  const u16* Bg = Bt + (size_t)(bn * 128 + w * 32 + (l >> 3)) * K + sg * 8;

  auto stage = [&](int buf, int k0) {
    gload_lds16(Ag + k0,                  &As[buf][(w * 16 + 0) * 64]);
    gload_lds16(Ag + (size_t)8 * K + k0,  &As[buf][(w * 16 + 8) * 64]);
    gload_lds16(Bg + k0,                  &Bs[buf][(w * 32 + 0) * 64]);
    gload_lds16(Bg + (size_t)8 * K + k0,  &Bs[buf][(w * 32 + 8) * 64]);
    gload_lds16(Bg + (size_t)16 * K + k0, &Bs[buf][(w * 32 + 16) * 64]);
    gload_lds16(Bg + (size_t)24 * K + k0, &Bs[buf][(w * 32 + 24) * 64]);
  };

  stage(0, 0);
  __syncthreads();
  int cur = 0;
  for (int k0 = 0; k0 < K; k0 += 64) {
    if (k0 + 64 < K) stage(cur ^ 1, k0 + 64);
#pragma unroll
    for (int s = 0; s < 2; ++s) {
      bf16x8 af[4], bf[2];
#pragma unroll
      for (int m = 0; m < 4; ++m)
        af[m] = *(const bf16x8*)(&As[cur][(m * 16 + l15) * 64 + (((s * 4 + l4) ^ l7) * 8)]);
#pragma unroll
      for (int n = 0; n < 2; ++n)
        bf[n] = *(const bf16x8*)(&Bs[cur][(w * 32 + n * 16 + l15) * 64 + (((s * 4 + l4) ^ l7) * 8)]);
#pragma unroll
      for (int m = 0; m < 4; ++m)
#pragma unroll
        for (int n = 0; n < 2; ++n)
          acc[m][n] = __builtin_amdgcn_mfma_f32_16x16x32_bf16(af[m], bf[n], acc[m][n], 0, 0, 0);
    }
    __syncthreads();
    cur ^= 1;
  }

#pragma unroll
  for (int m = 0; m < 4; ++m) {
    const int row0 = bm * 64 + m * 16 + l4 * 4;
#pragma unroll
    for (int n = 0; n < 2; ++n) {
      const int col = bn * 128 + w * 32 + n * 16 + l15;
      const float bv = bias[col];
#pragma unroll
      for (int r = 0; r < 4; ++r)
        gemm_epi<EPI>(row0 + r, col, acc[m][n][r] + bv, N, res, outf, outb,
                      nullptr, nullptr, nullptr);
    }
  }
}

// ---------------- flash attention: split-kt, 32x32 swapped-QK^T -------------
// R11 structure (best measured: 65.4us, VGPR 96): 512 threads = 8 warps =
// 4 q-subtiles (qg) x 2 kt-halves (kh); (512,2) -> 128 VGPR cap, 16 waves/CU.
__global__ __launch_bounds__(512, 2) void flash_attn(const u16* __restrict__ Q,
                                                     const u16* __restrict__ Kg,
                                                     const u16* __restrict__ Vt,
                                                     const u16* __restrict__ adjC,
                                                     u16* __restrict__ O) {
  __shared__ u16 Ks[2][2][64 * 64];   // [kh][buf]
  __shared__ u16 Vs[2][2][64 * 64];
  __shared__ float lw[4][32];
  __shared__ float lsx[4][32];
  const int flat = blockIdx.x + 16 * blockIdx.y;       // 512 blocks
  const int virt = (flat & 7) * 64 + (flat >> 3);      // XCD-contiguous remap
  const int qt = virt & 15;
  const int bh = virt >> 4;
  const int b = bh >> 3, hh = bh & 7;
  const int tid = threadIdx.x;
  const int w = tid >> 6, l = tid & 63;
  const int kh = w >> 2, qg = w & 3;
  const int q32 = l & 31, hi = l >> 5;
  const int qglob = qt * 128 + qg * 32 + q32;

  const u16* Qb = Q  + (size_t)bh * CDIM * DKH;
  const u16* Kb = Kg + (size_t)bh * CDIM * DKH;
  const u16* Vb = Vt + (size_t)bh * DKH * CDIM;  // [dk][C]

  const int srow = qg * 16 + (l >> 3);
  const int sg   = (l & 7) ^ (l >> 3);  // pre-swizzled source granule
  const u16* Kg0 = Kb + (size_t)(srow + 0) * DKH + sg * 8;
  const u16* Kg1 = Kb + (size_t)(srow + 8) * DKH + sg * 8;
  const u16* Vg0 = Vb + (size_t)(srow + 0) * CDIM + sg * 8;
  const u16* Vg1 = Vb + (size_t)(srow + 8) * CDIM + sg * 8;

  bf16x8 qf[4];
#pragma unroll
  for (int s = 0; s < 4; ++s)
    qf[s] = *(const bf16x8*)(Qb + (size_t)qglob * DKH + s * 16 + hi * 8);

  const u16* adjQ = adjC + ((size_t)(b * 32) * 2048 + qglob) * 64 + hi * 32;

  f32x16 oa[2] = {};
  float lsum = 0.f;

  auto stage = [&](int buf, int ktr) {
    int kta = kh * 16 + ktr;
    gload_lds16(Kg0 + (size_t)kta * 4096, &Ks[kh][buf][(qg * 16 + 0) * 64]);
    gload_lds16(Kg1 + (size_t)kta * 4096, &Ks[kh][buf][(qg * 16 + 8) * 64]);
    gload_lds16(Vg0 + kta * 64, &Vs[kh][buf][(qg * 16 + 0) * 64]);
    gload_lds16(Vg1 + kta * 64, &Vs[kh][buf][(qg * 16 + 8) * 64]);
  };
  auto ajload = [&](u16x8* dst, int ktr) {
    const u16* p = adjQ + (size_t)(kh * 16 + ktr) * 131072;  // 2048*64 u16 per kt
#pragma unroll
    for (int i = 0; i < 4; ++i) dst[i] = *(const u16x8*)(p + i * 8);
  };
  auto computeQK = [&](const u16* KsB, const u16x8* av, f32x16* sa) {
#pragma unroll
    for (int m = 0; m < 2; ++m)
#pragma unroll
      for (int r = 0; r < 16; ++r)
        sa[m][r] = bf2f(av[m * 2 + (r >> 3)][r & 7]);
    __builtin_amdgcn_s_setprio(1);
#pragma unroll
    for (int s = 0; s < 4; ++s)
#pragma unroll
      for (int m = 0; m < 2; ++m) {
        bf16x8 kf = *(const bf16x8*)(&KsB[(m * 32 + q32) * 64 + (((s * 2 + hi) ^ (q32 & 7)) * 8)]);
        sa[m] = __builtin_amdgcn_mfma_f32_32x32x16_bf16(kf, qf[s], sa[m], 0, 0, 0);
      }
    __builtin_amdgcn_s_setprio(0);
  };
  auto computePV = [&](const u16* VsB, f32x16* sa) {
#pragma unroll
    for (int m = 0; m < 2; ++m)
#pragma unroll
      for (int r = 0; r < 16; ++r) {
        float p = fexp2(sa[m][r]);
        sa[m][r] = p;
        lsum += p;
      }
    bf16x8 af[4];
#pragma unroll
    for (int m = 0; m < 2; ++m)
#pragma unroll
      for (int t2 = 0; t2 < 2; ++t2) {
        u32 w0 = pk2(sa[m][t2 * 8 + 0], sa[m][t2 * 8 + 1]);
        u32 w1 = pk2(sa[m][t2 * 8 + 2], sa[m][t2 * 8 + 3]);
        u32 w2 = pk2(sa[m][t2 * 8 + 4], sa[m][t2 * 8 + 5]);
        u32 w3 = pk2(sa[m][t2 * 8 + 6], sa[m][t2 * 8 + 7]);
        auto r02 = __builtin_amdgcn_permlane32_swap(w0, w2, false, false);
        auto r13 = __builtin_amdgcn_permlane32_swap(w1, w3, false, false);
        u32x4 aw;
        aw[0] = r02[0];
        aw[1] = r13[0];
        aw[2] = r02[1];
        aw[3] = r13[1];
        af[m * 2 + t2] = __builtin_bit_cast(bf16x8, aw);
      }
    __builtin_amdgcn_s_setprio(1);
#pragma unroll
    for (int s = 0; s < 4; ++s)
#pragma unroll
      for (int n = 0; n < 2; ++n) {
        bf16x8 vf = *(const bf16x8*)(&VsB[(n * 32 + q32) * 64 + (((s * 2 + hi) ^ (q32 & 7)) * 8)]);
        oa[n] = __builtin_amdgcn_mfma_f32_32x32x16_bf16(af[s], vf, oa[n], 0, 0, 0);
      }
    __builtin_amdgcn_s_setprio(0);
  };

  u16x8 avA[4], avB[4];
  f32x16 sa[2];
  stage(0, 0);
  ajload(avA, 0);
  __syncthreads();
#pragma unroll 1
  for (int it = 0; it < 8; ++it) {
    int ktr = it * 2;
    stage(1, ktr + 1);
    computeQK(&Ks[kh][0][0], avA, sa);
    ajload(avB, ktr + 1);           // prefetch next adj under PV
    computePV(&Vs[kh][0][0], sa);
    __syncthreads();
    if (ktr + 2 < 16) stage(0, ktr + 2);
    computeQK(&Ks[kh][1][0], avB, sa);
    if (ktr + 2 < 16) ajload(avA, ktr + 2);
    computePV(&Vs[kh][1][0], sa);
    __syncthreads();
  }

  // lane + partner(l^32) hold complementary k-halves of this kh's range
  lsum += __shfl_xor(lsum, 32);

  // combine kh halves through LDS (K/V buffers are dead now)
  float* cb = (float*)&Vs[0][0][0];   // 32KB: exactly the Vs space
  if (kh == 1) {
#pragma unroll
    for (int n = 0; n < 2; ++n)
#pragma unroll
      for (int r = 0; r < 16; ++r)
        cb[((qg * 2 + n) * 16 + r) * 64 + l] = oa[n][r];
    if (hi == 0) lsx[qg][q32] = lsum;
  }
  __syncthreads();
  if (kh == 0) {
    lsum += lsx[qg][q32];
#pragma unroll
    for (int n = 0; n < 2; ++n)
#pragma unroll
      for (int r = 0; r < 16; ++r)
        oa[n][r] += cb[((qg * 2 + n) * 16 + r) * 64 + l];
    lw[qg][q32] = 1.0f / lsum;
    // write attn_out: row-major [8192][512] bf16, col offset hh*64
#pragma unroll
    for (int n = 0; n < 2; ++n)
#pragma unroll
      for (int r = 0; r < 16; ++r) {
        int qloc = (r & 3) + 8 * (r >> 2) + 4 * hi;
        int row = qt * 128 + qg * 32 + qloc;
        float val = oa[n][r] * lw[qg][qloc];
        O[((size_t)b * CDIM + row) * DDIM + hh * 64 + n * 32 + q32] = f2bf(val);
      }
  }
}

extern "C" void kernel_launch(void* const* d_in, const int* in_sizes, int n_in,
                              void* d_out, int out_size, void* d_ws, size_t ws_size,
                              hipStream_t stream) {
  const float* h      = (const float*)d_in[0];
  const float* adj    = (const float*)d_in[1];
  const float* w_qkv  = (const float*)d_in[2];
  const float* b_qkv  = (const float*)d_in[3];
  const float* w_out  = (const float*)d_in[4];
  const float* b_out  = (const float*)d_in[5];
  const float* ln1g   = (const float*)d_in[6];
  const float* ln1b   = (const float*)d_in[7];
  const float* ln2g   = (const float*)d_in[8];
  const float* ln2b   = (const float*)d_in[9];
  const float* w1     = (const float*)d_in[10];
  const float* b1     = (const float*)d_in[11];
  const float* w2     = (const float*)d_in[12];
  const float* b2     = (const float*)d_in[13];
  float* out = (float*)d_out;

  char* ws = (char*)d_ws;
  u16* adjC  = (u16*)(ws);                      // 32 MiB exactly, dead after flash
  u16* hn    = (u16*)(ws + 33554432);           // 8 MiB; reused as ff_in
  u16* qb    = (u16*)(ws + 41943040);           // q head-major; later ffmid spans qb+kb
  u16* kb    = (u16*)(ws + 50331648);
  u16* vt    = (u16*)(ws + 58720256);           // V transposed [bh][dk][C]
  u16* attn  = (u16*)(ws + 67108864);
  u16* wqkvt = (u16*)(ws + 75497472);           // 1536x512 bf16 = 1.5MiB
  u16* woutt = (u16*)(ws + 77070336);           // 512x512
  u16* w1t   = (u16*)(ws + 77594624);           // 1024x512
  u16* w2t   = (u16*)(ws + 78643200);           // 512x1024
  u16* ffin  = hn;
  u16* ffmid = qb;   // 16MiB spans qb+kb (both dead after flash_attn)

  setup_kernel<<<3072, 256, 0, stream>>>(h, ln1g, ln1b, hn,
                                         w_qkv, w_out, w1, w2,
                                         wqkvt, woutt, w1t, w2t);

  qkv_adj_kernel<<<1792, 256, 0, stream>>>(hn, wqkvt, b_qkv, qb, kb, vt,
                                           adj, adjC);

  flash_attn<<<dim3(16, 32), 512, 0, stream>>>(qb, kb, vt, adjC, attn);

  gemm64<1><<<dim3(4, 128), 256, 0, stream>>>(attn, woutt, b_out, h,
                                              out, nullptr, NROW, DDIM, DDIM);

  ln_kernel<<<2048, 256, 0, stream>>>(out, ln2g, ln2b, ffin);

  gemm128k<2><<<dim3(8, 64), 256, 0, stream>>>(ffin, w1t, b1, nullptr,
                                               nullptr, ffmid, NROW, 2 * DDIM, DDIM);

  gemm64<1><<<dim3(4, 128), 256, 0, stream>>>(ffmid, w2t, b2, out,
                                              out, nullptr, NROW, DDIM, 2 * DDIM);
}